// Round 1
// 2547.479 us; speedup vs baseline: 1.8673x; 1.8673x over previous
//
#include <hip/hip_runtime.h>
#include <math.h>

#define NSLOTS 32
#define DIM    1024
#define NTOK   2048
#define NROWS  32768
#define NBLK   16
#define BLK    128

#define MOM      0.95f
#define OMM      0.05f
#define MOM2     0.9025f   // 0.95^2
#define MOMOMM2  0.095f    // 2*0.95*0.05
#define OMM2     0.0025f   // 0.05^2
#define INV_TEMP (1.0f/0.35f)
#define COS_EPS  1e-8f
#define NORM_EPS 1e-12f

__device__ __forceinline__ float reduce_all(float v) {
    v += __shfl_xor(v, 32, 64);
    v += __shfl_xor(v, 16, 64);
    v += __shfl_xor(v, 8, 64);
    v += __shfl_xor(v, 4, 64);
    v += __shfl_xor(v, 2, 64);
    v += __shfl_xor(v, 1, 64);
    return v;
}

// 8-value halving butterfly over 64 lanes (old path).
__device__ __forceinline__ float reduce8(const float v[8], int lane) {
    const bool b5 = (lane & 32) != 0;
    const bool b4 = (lane & 16) != 0;
    const bool b3 = (lane & 8) != 0;
    float t[4];
#pragma unroll
    for (int k = 0; k < 4; ++k) {
        float send = b5 ? v[k] : v[k + 4];
        float recv = __shfl_xor(send, 32, 64);
        t[k] = (b5 ? v[k + 4] : v[k]) + recv;
    }
    float u[2];
#pragma unroll
    for (int k = 0; k < 2; ++k) {
        float send = b4 ? t[k] : t[k + 2];
        float recv = __shfl_xor(send, 16, 64);
        u[k] = (b4 ? t[k + 2] : t[k]) + recv;
    }
    float send = b3 ? u[0] : u[1];
    float recv = __shfl_xor(send, 8, 64);
    float r = (b3 ? u[1] : u[0]) + recv;
    r += __shfl_xor(r, 4, 64);
    r += __shfl_xor(r, 2, 64);
    r += __shfl_xor(r, 1, 64);
    return r;
}

// 4-value variant; result for r = (lane>>4)&3, shared by all 16 lanes of group.
__device__ __forceinline__ float reduce4(const float v[4], int lane) {
    const bool b5 = (lane & 32) != 0;
    const bool b4 = (lane & 16) != 0;
    float t[2];
#pragma unroll
    for (int k = 0; k < 2; ++k) {
        float send = b5 ? v[k] : v[k + 2];
        float recv = __shfl_xor(send, 32, 64);
        t[k] = (b5 ? v[k + 2] : v[k]) + recv;
    }
    float send = b4 ? t[0] : t[1];
    float recv = __shfl_xor(send, 16, 64);
    float r = (b4 ? t[1] : t[0]) + recv;
    r += __shfl_xor(r, 8, 64);
    r += __shfl_xor(r, 4, 64);
    r += __shfl_xor(r, 2, 64);
    r += __shfl_xor(r, 1, 64);
    return r;
}

// ---------------------------------------------------------------------------
// DPP argmax step: merge (bv,bi) with the DPP-permuted partner.
// Tie-break: larger value wins; equal value -> smaller index (first-max).
// ---------------------------------------------------------------------------
template<int C>
__device__ __forceinline__ void argmax_dpp_step(float& bv, int& bi) {
    float ov = __int_as_float(__builtin_amdgcn_update_dpp(
        __float_as_int(bv), __float_as_int(bv), C, 0xf, 0xf, true));
    int oi = __builtin_amdgcn_update_dpp(bi, bi, C, 0xf, 0xf, true);
    if (ov > bv || (ov == bv && oi < bi)) { bv = ov; bi = oi; }
}

// ===========================================================================
// NEW PATH
// ===========================================================================

// G upper-triangle blocks: grid = 136 pairs * 4 i-quarters = 544 wgs, 256 thr.
// Tile: 32 rows (arow..+32) x 128 cols (brow..+128), K staged in LDS (KC=64).
#define GKC 64
__global__ __launch_bounds__(256, 1) void gram_kernel(
    const float* __restrict__ wb, float* __restrict__ G)
{
    __shared__ float As[GKC * 36];     // [k][i], i<32, stride 36 (16B-aligned rows)
    __shared__ float Bs[GKC * 132];    // [k][j], j<128, stride 132

    int p = blockIdx.x >> 2, iq = blockIdx.x & 3;
    int bi = 0, base = 0;
    while (p >= base + (NBLK - bi)) { base += NBLK - bi; ++bi; }
    const int bj = bi + (p - base);
    const int arow = bi * BLK + iq * 32;
    const int brow = bj * BLK;
    const int tid = threadIdx.x;
    const int jl = tid & 127;
    const int ih = tid >> 7;        // 0..1 -> rows ih*16..+16

    float acc[16];
#pragma unroll
    for (int c = 0; c < 16; ++c) acc[c] = 0.0f;

#pragma unroll 1
    for (int kc = 0; kc < DIM; kc += GKC) {
        __syncthreads();
        for (int v = tid; v < 32 * GKC / 4; v += 256) {
            int row = v >> 4, f = v & 15;
            float4 x = *(const float4*)&wb[(size_t)(arow + row) * DIM + kc + 4 * f];
            As[(4 * f + 0) * 36 + row] = x.x;
            As[(4 * f + 1) * 36 + row] = x.y;
            As[(4 * f + 2) * 36 + row] = x.z;
            As[(4 * f + 3) * 36 + row] = x.w;
        }
        for (int v = tid; v < 128 * GKC / 4; v += 256) {
            int row = v >> 4, f = v & 15;
            float4 x = *(const float4*)&wb[(size_t)(brow + row) * DIM + kc + 4 * f];
            Bs[(4 * f + 0) * 132 + row] = x.x;
            Bs[(4 * f + 1) * 132 + row] = x.y;
            Bs[(4 * f + 2) * 132 + row] = x.z;
            Bs[(4 * f + 3) * 132 + row] = x.w;
        }
        __syncthreads();
#pragma unroll 1
        for (int k = 0; k < GKC; ++k) {
            float bv = Bs[k * 132 + jl];
            const float4* ap = (const float4*)&As[k * 36 + ih * 16];
            float4 A0 = ap[0], A1 = ap[1], A2 = ap[2], A3 = ap[3];
            acc[0]  = fmaf(A0.x, bv, acc[0]);
            acc[1]  = fmaf(A0.y, bv, acc[1]);
            acc[2]  = fmaf(A0.z, bv, acc[2]);
            acc[3]  = fmaf(A0.w, bv, acc[3]);
            acc[4]  = fmaf(A1.x, bv, acc[4]);
            acc[5]  = fmaf(A1.y, bv, acc[5]);
            acc[6]  = fmaf(A1.z, bv, acc[6]);
            acc[7]  = fmaf(A1.w, bv, acc[7]);
            acc[8]  = fmaf(A2.x, bv, acc[8]);
            acc[9]  = fmaf(A2.y, bv, acc[9]);
            acc[10] = fmaf(A2.z, bv, acc[10]);
            acc[11] = fmaf(A2.w, bv, acc[11]);
            acc[12] = fmaf(A3.x, bv, acc[12]);
            acc[13] = fmaf(A3.y, bv, acc[13]);
            acc[14] = fmaf(A3.z, bv, acc[14]);
            acc[15] = fmaf(A3.w, bv, acc[15]);
        }
    }
#pragma unroll
    for (int c = 0; c < 16; ++c) {
        int i = arow + ih * 16 + c;
        G[(size_t)i * NTOK + brow + jl] = acc[c];
    }
}

// D0[s][t] = dot(slots0[s], wb[t]); grid = 256 wgs * 256 thr (8 tokens each)
__global__ __launch_bounds__(256, 1) void slotdot_kernel(
    const float* __restrict__ wb, const float* __restrict__ slots_in,
    float* __restrict__ D)
{
    __shared__ float tokL[8 * DIM];
    const int tid = threadIdx.x;
    const int t0 = blockIdx.x * 8;
    for (int v = tid; v < 8 * DIM / 4; v += 256)
        *(float4*)&tokL[4 * v] = *(const float4*)&wb[(size_t)t0 * DIM + 4 * v];
    __syncthreads();
    const int s = tid & 31, tl = tid >> 5;
    const float* sp = slots_in + s * DIM;
    const float* tp = tokL + tl * DIM;
    float acc = 0.0f;
    for (int d = 0; d < DIM; d += 4) {
        float4 a = *(const float4*)&sp[d];
        float4 t = *(const float4*)&tp[d];
        acc = fmaf(a.x, t.x, acc); acc = fmaf(a.y, t.y, acc);
        acc = fmaf(a.z, t.z, acc); acc = fmaf(a.w, t.w, acc);
    }
    D[s * NTOK + t0 + tl] = acc;
}

// ---------------------------------------------------------------------------
// Sequential routing scan, Gram-matrix form. 1 block x 512 threads.
// Hot loop runs on wave 0 only (zero barriers, zero dim-1024 work).
// ---------------------------------------------------------------------------
__global__ __launch_bounds__(512, 1) void scan_kernel(
    const float* __restrict__ slots_in,
    const float* __restrict__ usage_in,
    const float* __restrict__ G,
    float* __restrict__ D,
    int* __restrict__ listG,
    float* __restrict__ coefG,
    int* __restrict__ offG,
    float* __restrict__ decayTotG,
    float* __restrict__ nsG)
{
    __shared__ float DblkL[BLK * 33];     // [i][s], stride 33 (bank-spread)
    __shared__ float pow95L[2049];
    __shared__ int   idxAllL[NTOK];
    __shared__ int   rankAllL[NTOK];
    __shared__ int   Mhist[NBLK * 32];
    __shared__ int   preL[NBLK * 32];
    __shared__ int   sufL[NBLK * 32];
    __shared__ float nt2L[BLK];
    __shared__ float invntL[BLK];
    __shared__ int   MblkL[32];
    __shared__ float decayL[32];
    __shared__ int   offL[33];
    __shared__ int   listL[BLK];
    __shared__ float coefL[BLK];
    __shared__ int   MtotL[32];
    __shared__ int   globOffL[33];

    const int tid = threadIdx.x;
    const int w = tid >> 6;
    const int j = tid & 63;

    // 0.95^k table (accuracy ~1 ulp of exp2; feeds coefs whose total error
    // is far below the EMA's own f32 rounding)
    const float l295 = log2f(0.95f);
    for (int k = tid; k < 2049; k += 512) pow95L[k] = exp2f((float)k * l295);
    // block-0 column preload from D0
    for (int e = tid; e < BLK * 32; e += 512) {
        int i = e >> 5, s = e & 31;
        DblkL[i * 33 + s] = D[s * NTOK + i];
    }
    __syncthreads();

    // wave-0 persistent per-lane state: lane s owns slot s (s = j for j<32)
    float ssd = 0.0f, invns = 0.0f;
    unsigned emptyMask = 0;
    if (w == 0) {
        if (j < 32) {
            const float* sr = slots_in + j * DIM;
            float a = 0.0f;
            for (int d = 0; d < DIM; d += 4) {
                float4 v = *(const float4*)&sr[d];
                a = fmaf(v.x, v.x, a); a = fmaf(v.y, v.y, a);
                a = fmaf(v.z, v.z, a); a = fmaf(v.w, v.w, a);
            }
            ssd = a;
            invns = 1.0f / fmaxf(sqrtf(ssd), COS_EPS);
        }
        for (int s = 0; s < 32; ++s)
            if (usage_in[s] == 0.0f) emptyMask |= (1u << s);
    }

#pragma unroll 1
    for (int b = 0; b < NBLK; ++b) {
        const int t0 = b * BLK;
        // phase A: token norms for this block (from G diagonal)
        for (int i = tid; i < BLK; i += 512) {
            float g = G[(size_t)(t0 + i) * NTOK + t0 + i];
            nt2L[i] = g;
            invntL[i] = 1.0f / fmaxf(sqrtf(g), COS_EPS);
        }
        __syncthreads();

        if (w == 0) {
            int mcnt = 0;   // lane s: #assignments to slot s within this block
            const float* Gb = G + (size_t)t0 * NTOK + t0;
            // triple-buffered G-row prefetch: lane j holds cols j and 64+j
            float a0 = Gb[j],            a1 = Gb[64 + j];
            float b0 = Gb[NTOK + j],     b1 = Gb[NTOK + 64 + j];
            float c0 = Gb[2 * NTOK + j], c1 = Gb[2 * NTOK + 64 + j];
#pragma unroll 1
            for (int i = 0; i < BLK; ++i) {
                const float g0 = a0, g1 = a1;
                a0 = b0; a1 = b1; b0 = c0; b1 = c1;
                if (i + 3 < BLK) {
                    const float* gr = Gb + (size_t)(i + 3) * NTOK;
                    c0 = gr[j]; c1 = gr[64 + j];
                }
                const float dcol = DblkL[i * 33 + (j & 31)];
                const float nt2 = nt2L[i];
                int idx;
                if (emptyMask) {                      // uniform branch
                    idx = (int)__builtin_ctz(emptyMask);
                    emptyMask &= emptyMask - 1;
                } else {
                    float bv = dcol * invns * invntL[i];
                    int bi = j;
                    // lanes 32..63 hold garbage but DPP rows (16) and the
                    // xor16 swizzle never cross into lanes 0..31.
                    argmax_dpp_step<0xB1>(bv, bi);    // quad_perm xor1
                    argmax_dpp_step<0x4E>(bv, bi);    // quad_perm xor2
                    argmax_dpp_step<0x124>(bv, bi);   // row_ror:4
                    argmax_dpp_step<0x128>(bv, bi);   // row_ror:8
                    {
                        float ov = __int_as_float(__builtin_amdgcn_ds_swizzle(
                            __float_as_int(bv), 0x401F));   // xor16
                        int oi = __builtin_amdgcn_ds_swizzle(bi, 0x401F);
                        if (ov > bv || (ov == bv && oi < bi)) { bv = ov; bi = oi; }
                    }
                    idx = __builtin_amdgcn_readfirstlane(bi);
                }
                if (j == idx) {                       // owning lane bookkeeping
                    rankAllL[t0 + i] = mcnt;
                    ++mcnt;
                    // ||0.95 a + 0.05 b||^2 = 0.9025||a||^2 + 0.095 a.b + 0.0025||b||^2
                    ssd = MOM2 * ssd + MOMOMM2 * dcol + OMM2 * nt2;
                    invns = 1.0f / fmaxf(sqrtf(ssd), COS_EPS);
                }
                if (j == 0) idxAllL[t0 + i] = idx;
                // row-update future in-block columns: lane j owns rows j, 64+j
                if (j > i) {
                    int a = j * 33 + idx;
                    DblkL[a] = MOM * DblkL[a] + OMM * g0;
                }
                {
                    int t2 = 64 + j;
                    if (t2 > i) {
                        int a = t2 * 33 + idx;
                        DblkL[a] = MOM * DblkL[a] + OMM * g1;
                    }
                }
            }
            if (j < 32) {
                MblkL[j] = mcnt;
                Mhist[b * 32 + j] = mcnt;
                decayL[j] = pow95L[mcnt];
            }
            if (j == 0) {
                int o = 0;
                for (int s = 0; s < 32; ++s) { offL[s] = o; o += MblkL[s]; }
                offL[32] = o;
            }
        }
        __syncthreads();

        if (b < NBLK - 1) {
            // phase B: per-slot token lists + closed-form coefs for this block
            if (tid < BLK) {
                int idx = idxAllL[t0 + tid];
                int r = rankAllL[t0 + tid];
                int p = offL[idx] + r;
                listL[p] = tid;
                coefL[p] = OMM * pow95L[MblkL[idx] - 1 - r];
            }
            __syncthreads();
            // phase C: batched update of all future D columns (all 512 thr);
            // next block's columns go straight into LDS.
            {
                const int tp = t0 + BLK + 4 * tid;
                if (tp < NTOK) {
                    const bool toLds = (4 * tid) < BLK;
#pragma unroll 1
                    for (int s = 0; s < 32; ++s) {
                        const float dec = decayL[s];
                        const float4 dv = *(const float4*)&D[s * NTOK + tp];
                        float ax = dec * dv.x, ay = dec * dv.y;
                        float az = dec * dv.z, aw = dec * dv.w;
                        const int k1 = offL[s + 1];
#pragma unroll 1
                        for (int k = offL[s]; k < k1; ++k) {
                            const int ii = listL[k];
                            const float c = coefL[k];
                            const float4 gv =
                                *(const float4*)&G[(size_t)(t0 + ii) * NTOK + tp];
                            ax = fmaf(c, gv.x, ax); ay = fmaf(c, gv.y, ay);
                            az = fmaf(c, gv.z, az); aw = fmaf(c, gv.w, aw);
                        }
                        if (toLds) {
                            const int r0 = 4 * tid;
                            DblkL[(r0 + 0) * 33 + s] = ax;
                            DblkL[(r0 + 1) * 33 + s] = ay;
                            DblkL[(r0 + 2) * 33 + s] = az;
                            DblkL[(r0 + 3) * 33 + s] = aw;
                        } else {
                            float4 o; o.x = ax; o.y = ay; o.z = az; o.w = aw;
                            *(float4*)&D[s * NTOK + tp] = o;
                        }
                    }
                }
            }
            __syncthreads();
        }
    }

    __syncthreads();
    // epilogue: global per-slot lists + coefs for slot materialization
    if (tid < 32) {
        int acc = 0;
        for (int bb = 0; bb < NBLK; ++bb) {
            preL[bb * 32 + tid] = acc;
            acc += Mhist[bb * 32 + tid];
        }
        MtotL[tid] = acc;
        int sacc = 0;
        for (int bb = NBLK - 1; bb >= 0; --bb) {
            sufL[bb * 32 + tid] = sacc;
            sacc += Mhist[bb * 32 + tid];
        }
    }
    __syncthreads();
    if (tid == 0) {
        int o = 0;
        for (int s = 0; s < 32; ++s) { globOffL[s] = o; o += MtotL[s]; }
        globOffL[32] = o;
    }
    __syncthreads();
    if (tid < 33) offG[tid] = globOffL[tid];
    if (tid < 32) {
        decayTotG[tid] = pow95L[MtotL[tid]];
        nsG[tid] = sqrtf(ssd);     // tid<32 ARE wave-0 lanes 0..31
    }
    for (int t = tid; t < NTOK; t += 512) {
        const int s = idxAllL[t];
        const int bb = t >> 7;
        const int r = rankAllL[t];
        const int pos = globOffL[s] + preL[bb * 32 + s] + r;
        const int e = (Mhist[bb * 32 + s] - 1 - r) + sufL[bb * 32 + s];
        listG[pos] = t;
        coefG[pos] = OMM * pow95L[e];
    }
}

// Materialize normalized slots: sn[s] = (0.95^M * slots0[s] + sum coef*tok)/ns
__global__ __launch_bounds__(256, 1) void mat_kernel(
    const float* __restrict__ wb, const float* __restrict__ slots_in,
    const float* __restrict__ coefG, const int* __restrict__ listG,
    const int* __restrict__ offG, const float* __restrict__ decayTotG,
    const float* __restrict__ nsG, float* __restrict__ sn)
{
    const int s = blockIdx.x >> 2;
    const int d = (blockIdx.x & 3) * 256 + threadIdx.x;
    float acc = decayTotG[s] * slots_in[s * DIM + d];
    const int k1 = offG[s + 1];
    for (int k = offG[s]; k < k1; ++k) {
        const int t = listG[k];
        acc = fmaf(coefG[k], wb[(size_t)t * DIM + d], acc);
    }
    sn[s * DIM + d] = acc * (1.0f / fmaxf(nsG[s], NORM_EPS));
}

// ===========================================================================
// OLD PATH (fallback if workspace is too small for G) — unchanged
// ===========================================================================

#define UPDATE_SLOT(i) { _Pragma("unroll") \
    for (int k = 0; k < 16; ++k) sreg[i][k] = MOM * sreg[i][k] + OMM * tv[k]; }

__global__ __launch_bounds__(256, 1) void scan_seq_kernel(
    const float* __restrict__ wb,
    const float* __restrict__ slots_in,
    const float* __restrict__ usage_in,
    float* __restrict__ sn_out,
    float* __restrict__ ns_out)
{
    const int tid = threadIdx.x;
    const int w = tid >> 6;
    const int j = tid & 63;

    __shared__ __align__(16) float tokL[DIM];
    __shared__ float ntp[4];
    __shared__ float simsL[NSLOTS];

    float sreg[8][16];
#pragma unroll
    for (int i = 0; i < 8; ++i) {
        const int s = 8 * w + i;
#pragma unroll
        for (int q = 0; q < 4; ++q) {
            float4 v = *(const float4*)&slots_in[s * DIM + 256 * q + 4 * j];
            sreg[i][4*q+0] = v.x; sreg[i][4*q+1] = v.y;
            sreg[i][4*q+2] = v.z; sreg[i][4*q+3] = v.w;
        }
    }
    float ssd;
    {
        float v[8];
#pragma unroll
        for (int i = 0; i < 8; ++i) {
            float a = 0.0f;
#pragma unroll
            for (int k = 0; k < 16; ++k) a = fmaf(sreg[i][k], sreg[i][k], a);
            v[i] = a;
        }
        ssd = reduce8(v, j);
    }
    unsigned emptyMask = 0;
    for (int s = 0; s < NSLOTS; ++s)
        if (usage_in[s] == 0.0f) emptyMask |= (1u << s);

    float4 gA = *(const float4*)&wb[0 * DIM + 4 * tid];
    float4 gB = *(const float4*)&wb[1 * DIM + 4 * tid];

#pragma unroll 1
    for (int t = 0; t < NTOK; ++t) {
        const float4 gc = gA;
        gA = gB;
        if (t + 2 < NTOK) gB = *(const float4*)&wb[(t + 2) * DIM + 4 * tid];

        *(float4*)&tokL[4 * tid] = gc;
        float s2 = gc.x*gc.x + gc.y*gc.y + gc.z*gc.z + gc.w*gc.w;
        s2 = reduce_all(s2);
        if (j == 0) ntp[w] = s2;
        __syncthreads();

        const float nt2 = ntp[0] + ntp[1] + ntp[2] + ntp[3];
        const float invnt = 1.0f / fmaxf(sqrtf(nt2), COS_EPS);

        float tv[16];
#pragma unroll
        for (int q = 0; q < 4; ++q) {
            float4 tq = *(const float4*)&tokL[256 * q + 4 * j];
            tv[4*q+0] = tq.x; tv[4*q+1] = tq.y; tv[4*q+2] = tq.z; tv[4*q+3] = tq.w;
        }
        float vv[8];
#pragma unroll
        for (int i = 0; i < 8; ++i) {
            float a = 0.0f;
#pragma unroll
            for (int k = 0; k < 16; ++k) a = fmaf(sreg[i][k], tv[k], a);
            vv[i] = a;
        }
        const float dotd = reduce8(vv, j);
        const float invd = 1.0f / fmaxf(sqrtf(ssd), COS_EPS);
        if ((j & 7) == 0) simsL[8 * w + (j >> 3)] = dotd * invd * invnt;
        __syncthreads();

        int idx;
        if (emptyMask) {
            idx = (int)__builtin_ctz(emptyMask);
            emptyMask &= ~(1u << idx);
        } else {
            float bv = simsL[j & 31];
            int bi = j & 31;
#pragma unroll
            for (int m = 1; m < 64; m <<= 1) {
                float ov = __shfl_xor(bv, m, 64);
                int   oi = __shfl_xor(bi, m, 64);
                if (ov > bv || (ov == bv && oi < bi)) { bv = ov; bi = oi; }
            }
            idx = bi;
        }

        if ((idx >> 3) == w) {
            switch (idx & 7) {
                case 0: UPDATE_SLOT(0); break;
                case 1: UPDATE_SLOT(1); break;
                case 2: UPDATE_SLOT(2); break;
                case 3: UPDATE_SLOT(3); break;
                case 4: UPDATE_SLOT(4); break;
                case 5: UPDATE_SLOT(5); break;
                case 6: UPDATE_SLOT(6); break;
                case 7: UPDATE_SLOT(7); break;
            }
            if ((j >> 3) == (idx & 7))
                ssd = MOM2 * ssd + MOMOMM2 * dotd + OMM2 * nt2;
        }
    }

    const float nsv = sqrtf(ssd);
    if ((j & 7) == 0) ns_out[8 * w + (j >> 3)] = nsv;
#pragma unroll
    for (int i = 0; i < 8; ++i) {
        const float ns_i = __shfl(nsv, i << 3, 64);
        const float inv_i = 1.0f / fmaxf(ns_i, NORM_EPS);
        const int s = 8 * w + i;
#pragma unroll
        for (int q = 0; q < 4; ++q) {
            float4 o;
            o.x = sreg[i][4*q+0] * inv_i;
            o.y = sreg[i][4*q+1] * inv_i;
            o.z = sreg[i][4*q+2] * inv_i;
            o.w = sreg[i][4*q+3] * inv_i;
            *(float4*)&sn_out[s * DIM + 256 * q + 4 * j] = o;
        }
    }
}

// ---------------------------------------------------------------------------
// Retrieve: unchanged from the passing kernel.
// ---------------------------------------------------------------------------
__global__ __launch_bounds__(512, 2) void retrieve_kernel(
    const float* __restrict__ x,
    const float* __restrict__ sn_g,
    const float* __restrict__ ns_g,
    float* __restrict__ out)
{
    __shared__ __align__(16) float snL[8 * DIM];
    __shared__ float nsL[NSLOTS];
    __shared__ __align__(16) float scL[8 * 4 * NSLOTS];

    const int tid = threadIdx.x;
    const int w = tid >> 6;
    const int j = tid & 63;

    if (tid < NSLOTS) nsL[tid] = ns_g[tid];

    const int rowbase = (blockIdx.x * 8 + w) * 4;

    float xv[4][16];
#pragma unroll
    for (int r = 0; r < 4; ++r) {
        const float* xr = &x[(long)(rowbase + r) * DIM];
#pragma unroll
        for (int q = 0; q < 4; ++q) {
            float4 v = *(const float4*)&xr[256 * q + 4 * j];
            xv[r][4*q+0] = v.x; xv[r][4*q+1] = v.y;
            xv[r][4*q+2] = v.z; xv[r][4*q+3] = v.w;
        }
    }
    float mul[4];
#pragma unroll
    for (int r = 0; r < 4; ++r) {
        float a = 0.0f;
#pragma unroll
        for (int k = 0; k < 16; ++k) a = fmaf(xv[r][k], xv[r][k], a);
        a = reduce_all(a);
        mul[r] = (1.0f / fmaxf(sqrtf(a), NORM_EPS)) * INV_TEMP;
    }

#pragma unroll 1
    for (int h = 0; h < 4; ++h) {
        if (h) __syncthreads();
        for (int i = tid; i < 8 * DIM / 4; i += 512)
            *(float4*)&snL[4 * i] = *(const float4*)&sn_g[h * 8 * DIM + 4 * i];
        __syncthreads();
#pragma unroll 1
        for (int si = 0; si < 8; ++si) {
            const int s = 8 * h + si;
            float snv[16];
#pragma unroll
            for (int q = 0; q < 4; ++q) {
                float4 v = *(const float4*)&snL[si * DIM + 256 * q + 4 * j];
                snv[4*q+0]=v.x; snv[4*q+1]=v.y; snv[4*q+2]=v.z; snv[4*q+3]=v.w;
            }
            float p[4];
#pragma unroll
            for (int r = 0; r < 4; ++r) {
                float a = 0.0f;
#pragma unroll
                for (int k = 0; k < 16; ++k) a = fmaf(xv[r][k], snv[k], a);
                p[r] = a;
            }
            float d = reduce4(p, j);
            if ((j & 15) == 0) scL[w * 128 + (j >> 4) * 32 + s] = d;
        }
    }

    {
        const int r = j & 3;
        const float mulr = (r == 0) ? mul[0] : (r == 1) ? mul[1]
                         : (r == 2) ? mul[2] : mul[3];
        float sc[32];
#pragma unroll
        for (int s4 = 0; s4 < 8; ++s4) {
            float4 v = *(const float4*)&scL[w * 128 + r * 32 + 4 * s4];
            sc[4*s4+0]=v.x; sc[4*s4+1]=v.y; sc[4*s4+2]=v.z; sc[4*s4+3]=v.w;
        }
        float m = -INFINITY;
#pragma unroll
        for (int s = 0; s < 32; ++s) { sc[s] *= mulr; m = fmaxf(m, sc[s]); }
        float sum = 0.0f;
#pragma unroll
        for (int s = 0; s < 32; ++s) { sc[s] = expf(sc[s] - m); sum += sc[s]; }
        const float isum = 1.0f / sum;
        if (j < 4) {
#pragma unroll
            for (int s4 = 0; s4 < 8; ++s4) {
                float4 o;
                o.x = sc[4*s4+0] * isum * nsL[4*s4+0];
                o.y = sc[4*s4+1] * isum * nsL[4*s4+1];
                o.z = sc[4*s4+2] * isum * nsL[4*s4+2];
                o.w = sc[4*s4+3] * isum * nsL[4*s4+3];
                *(float4*)&scL[w * 128 + j * 32 + 4 * s4] = o;
            }
        }
    }

    float acc[4][16];
#pragma unroll
    for (int r = 0; r < 4; ++r)
#pragma unroll
        for (int k = 0; k < 16; ++k) acc[r][k] = 0.0f;

#pragma unroll 1
    for (int h = 3; h >= 0; --h) {
        if (h != 3) {
            __syncthreads();
            for (int i = tid; i < 8 * DIM / 4; i += 512)
                *(float4*)&snL[4 * i] = *(const float4*)&sn_g[h * 8 * DIM + 4 * i];
            __syncthreads();
        }
#pragma unroll 1
        for (int si = 0; si < 8; ++si) {
            const int s = 8 * h + si;
            float snv[16];
#pragma unroll
            for (int q = 0; q < 4; ++q) {
                float4 v = *(const float4*)&snL[si * DIM + 256 * q + 4 * j];
                snv[4*q+0]=v.x; snv[4*q+1]=v.y; snv[4*q+2]=v.z; snv[4*q+3]=v.w;
            }
#pragma unroll
            for (int r = 0; r < 4; ++r) {
                const float ww = scL[w * 128 + r * 32 + s];
#pragma unroll
                for (int k = 0; k < 16; ++k) acc[r][k] = fmaf(ww, snv[k], acc[r][k]);
            }
        }
    }

#pragma unroll
    for (int r = 0; r < 4; ++r) {
        float* orow = &out[(long)(rowbase + r) * DIM];
#pragma unroll
        for (int q = 0; q < 4; ++q) {
            float4 o;
            o.x = acc[r][4*q+0]; o.y = acc[r][4*q+1];
            o.z = acc[r][4*q+2]; o.w = acc[r][4*q+3];
            *(float4*)&orow[256 * q + 4 * j] = o;
        }
    }
}

extern "C" void kernel_launch(void* const* d_in, const int* in_sizes, int n_in,
                              void* d_out, int out_size, void* d_ws, size_t ws_size,
                              hipStream_t stream) {
    const float* x  = (const float*)d_in[0];   // [4,8192,1024]
    const float* wb = (const float*)d_in[1];   // [2048,1024]
    const float* sl = (const float*)d_in[2];   // [32,1024]
    const float* us = (const float*)d_in[3];   // [32]
    float* out = (float*)d_out;

    // workspace layout (floats)
    float* sn   = (float*)d_ws;                    // 32*1024
    float* nsG  = sn + NSLOTS * DIM;               // 32 (pad 64)
    float* D    = nsG + 64;                        // 32*2048
    float* G    = D + NSLOTS * NTOK;               // 2048*2048
    float* coefG = G + (size_t)NTOK * NTOK;        // 2048
    int* listG  = (int*)(coefG + NTOK);            // 2048
    int* offG   = listG + NTOK;                    // 33 (pad 64)
    float* decayTotG = (float*)(offG + 64);        // 32
    const size_t ws_need = (size_t)((decayTotG + 64) - sn) * sizeof(float);

    if (ws_size >= ws_need) {
        gram_kernel<<<dim3(136 * 4), dim3(256), 0, stream>>>(wb, G);
        slotdot_kernel<<<dim3(256), dim3(256), 0, stream>>>(wb, sl, D);
        scan_kernel<<<dim3(1), dim3(512), 0, stream>>>(
            sl, us, G, D, listG, coefG, offG, decayTotG, nsG);
        mat_kernel<<<dim3(128), dim3(256), 0, stream>>>(
            wb, sl, coefG, listG, offG, decayTotG, nsG, sn);
    } else {
        // fallback: proven sequential path
        scan_seq_kernel<<<dim3(1), dim3(256), 0, stream>>>(wb, sl, us, sn, nsG);
    }
    retrieve_kernel<<<dim3(NROWS / 32), dim3(512), 0, stream>>>(x, sn, nsG, out);
}

// Round 2
// 2501.951 us; speedup vs baseline: 1.9013x; 1.0182x over previous
//
#include <hip/hip_runtime.h>
#include <math.h>

#define NSLOTS 32
#define DIM    1024
#define NTOK   2048
#define NROWS  32768
#define NBLK   16
#define BLK    128

#define MOM      0.95f
#define OMM      0.05f
#define MOM2     0.9025f   // 0.95^2
#define MOMOMM2  0.095f    // 2*0.95*0.05
#define OMM2     0.0025f   // 0.05^2
#define INV_TEMP (1.0f/0.35f)
#define COS_EPS  1e-8f
#define NORM_EPS 1e-12f

__device__ __forceinline__ float reduce_all(float v) {
    v += __shfl_xor(v, 32, 64);
    v += __shfl_xor(v, 16, 64);
    v += __shfl_xor(v, 8, 64);
    v += __shfl_xor(v, 4, 64);
    v += __shfl_xor(v, 2, 64);
    v += __shfl_xor(v, 1, 64);
    return v;
}

// 8-value halving butterfly over 64 lanes (fallback path).
__device__ __forceinline__ float reduce8(const float v[8], int lane) {
    const bool b5 = (lane & 32) != 0;
    const bool b4 = (lane & 16) != 0;
    const bool b3 = (lane & 8) != 0;
    float t[4];
#pragma unroll
    for (int k = 0; k < 4; ++k) {
        float send = b5 ? v[k] : v[k + 4];
        float recv = __shfl_xor(send, 32, 64);
        t[k] = (b5 ? v[k + 4] : v[k]) + recv;
    }
    float u[2];
#pragma unroll
    for (int k = 0; k < 2; ++k) {
        float send = b4 ? t[k] : t[k + 2];
        float recv = __shfl_xor(send, 16, 64);
        u[k] = (b4 ? t[k + 2] : t[k]) + recv;
    }
    float send = b3 ? u[0] : u[1];
    float recv = __shfl_xor(send, 8, 64);
    float r = (b3 ? u[1] : u[0]) + recv;
    r += __shfl_xor(r, 4, 64);
    r += __shfl_xor(r, 2, 64);
    r += __shfl_xor(r, 1, 64);
    return r;
}

// 4-value variant; result for r = (lane>>4)&3, shared by all 16 lanes of group.
__device__ __forceinline__ float reduce4(const float v[4], int lane) {
    const bool b5 = (lane & 32) != 0;
    const bool b4 = (lane & 16) != 0;
    float t[2];
#pragma unroll
    for (int k = 0; k < 2; ++k) {
        float send = b5 ? v[k] : v[k + 2];
        float recv = __shfl_xor(send, 32, 64);
        t[k] = (b5 ? v[k + 2] : v[k]) + recv;
    }
    float send = b4 ? t[0] : t[1];
    float recv = __shfl_xor(send, 16, 64);
    float r = (b4 ? t[1] : t[0]) + recv;
    r += __shfl_xor(r, 8, 64);
    r += __shfl_xor(r, 4, 64);
    r += __shfl_xor(r, 2, 64);
    r += __shfl_xor(r, 1, 64);
    return r;
}

// ---------------------------------------------------------------------------
// DPP argmax step: merge (bv,bi) with the DPP-permuted partner.
// Tie-break: larger value wins; equal value -> smaller index (first-max).
// ---------------------------------------------------------------------------
template<int C>
__device__ __forceinline__ void argmax_dpp_step(float& bv, int& bi) {
    float ov = __int_as_float(__builtin_amdgcn_update_dpp(
        __float_as_int(bv), __float_as_int(bv), C, 0xf, 0xf, true));
    int oi = __builtin_amdgcn_update_dpp(bi, bi, C, 0xf, 0xf, true);
    if (ov > bv || (ov == bv && oi < bi)) { bv = ov; bi = oi; }
}

// ===========================================================================
// NEW PATH
// ===========================================================================

// G upper-triangle blocks: grid = 136 pairs * 4 i-quarters = 544 wgs, 256 thr.
#define GKC 64
__global__ __launch_bounds__(256, 1) void gram_kernel(
    const float* __restrict__ wb, float* __restrict__ G)
{
    __shared__ float As[GKC * 36];
    __shared__ float Bs[GKC * 132];

    int p = blockIdx.x >> 2, iq = blockIdx.x & 3;
    int bi = 0, base = 0;
    while (p >= base + (NBLK - bi)) { base += NBLK - bi; ++bi; }
    const int bj = bi + (p - base);
    const int arow = bi * BLK + iq * 32;
    const int brow = bj * BLK;
    const int tid = threadIdx.x;
    const int jl = tid & 127;
    const int ih = tid >> 7;

    float acc[16];
#pragma unroll
    for (int c = 0; c < 16; ++c) acc[c] = 0.0f;

#pragma unroll 1
    for (int kc = 0; kc < DIM; kc += GKC) {
        __syncthreads();
        for (int v = tid; v < 32 * GKC / 4; v += 256) {
            int row = v >> 4, f = v & 15;
            float4 x = *(const float4*)&wb[(size_t)(arow + row) * DIM + kc + 4 * f];
            As[(4 * f + 0) * 36 + row] = x.x;
            As[(4 * f + 1) * 36 + row] = x.y;
            As[(4 * f + 2) * 36 + row] = x.z;
            As[(4 * f + 3) * 36 + row] = x.w;
        }
        for (int v = tid; v < 128 * GKC / 4; v += 256) {
            int row = v >> 4, f = v & 15;
            float4 x = *(const float4*)&wb[(size_t)(brow + row) * DIM + kc + 4 * f];
            Bs[(4 * f + 0) * 132 + row] = x.x;
            Bs[(4 * f + 1) * 132 + row] = x.y;
            Bs[(4 * f + 2) * 132 + row] = x.z;
            Bs[(4 * f + 3) * 132 + row] = x.w;
        }
        __syncthreads();
#pragma unroll 1
        for (int k = 0; k < GKC; ++k) {
            float bv = Bs[k * 132 + jl];
            const float4* ap = (const float4*)&As[k * 36 + ih * 16];
            float4 A0 = ap[0], A1 = ap[1], A2 = ap[2], A3 = ap[3];
            acc[0]  = fmaf(A0.x, bv, acc[0]);
            acc[1]  = fmaf(A0.y, bv, acc[1]);
            acc[2]  = fmaf(A0.z, bv, acc[2]);
            acc[3]  = fmaf(A0.w, bv, acc[3]);
            acc[4]  = fmaf(A1.x, bv, acc[4]);
            acc[5]  = fmaf(A1.y, bv, acc[5]);
            acc[6]  = fmaf(A1.z, bv, acc[6]);
            acc[7]  = fmaf(A1.w, bv, acc[7]);
            acc[8]  = fmaf(A2.x, bv, acc[8]);
            acc[9]  = fmaf(A2.y, bv, acc[9]);
            acc[10] = fmaf(A2.z, bv, acc[10]);
            acc[11] = fmaf(A2.w, bv, acc[11]);
            acc[12] = fmaf(A3.x, bv, acc[12]);
            acc[13] = fmaf(A3.y, bv, acc[13]);
            acc[14] = fmaf(A3.z, bv, acc[14]);
            acc[15] = fmaf(A3.w, bv, acc[15]);
        }
    }
#pragma unroll
    for (int c = 0; c < 16; ++c) {
        int i = arow + ih * 16 + c;
        G[(size_t)i * NTOK + brow + jl] = acc[c];
    }
}

// D0[s][t] = dot(slots0[s], wb[t]); grid = 256 wgs * 256 thr (8 tokens each)
__global__ __launch_bounds__(256, 1) void slotdot_kernel(
    const float* __restrict__ wb, const float* __restrict__ slots_in,
    float* __restrict__ D)
{
    __shared__ float tokL[8 * DIM];
    const int tid = threadIdx.x;
    const int t0 = blockIdx.x * 8;
    for (int v = tid; v < 8 * DIM / 4; v += 256)
        *(float4*)&tokL[4 * v] = *(const float4*)&wb[(size_t)t0 * DIM + 4 * v];
    __syncthreads();
    const int s = tid & 31, tl = tid >> 5;
    const float* sp = slots_in + s * DIM;
    const float* tp = tokL + tl * DIM;
    float acc = 0.0f;
    for (int d = 0; d < DIM; d += 4) {
        float4 a = *(const float4*)&sp[d];
        float4 t = *(const float4*)&tp[d];
        acc = fmaf(a.x, t.x, acc); acc = fmaf(a.y, t.y, acc);
        acc = fmaf(a.z, t.z, acc); acc = fmaf(a.w, t.w, acc);
    }
    D[s * NTOK + t0 + tl] = acc;
}

// ---------------------------------------------------------------------------
// Sequential routing scan, Gram form. 1 block x 512 threads.
// Hot loop on wave 0: zero global loads, zero LDS-pipe ops on the argmax path.
// ---------------------------------------------------------------------------
__global__ __launch_bounds__(512, 1) void scan_kernel(
    const float* __restrict__ slots_in,
    const float* __restrict__ usage_in,
    const float* __restrict__ G,
    float* __restrict__ D,
    int* __restrict__ listG,
    float* __restrict__ coefG,
    int* __restrict__ offG,
    float* __restrict__ decayTotG,
    float* __restrict__ nsG)
{
    __shared__ float GdL[BLK * BLK + 4];        // 64KB staged diag block of G
    __shared__ float DblkL[(BLK + 1) * 33];     // [i][s], stride 33, +1 row pad
    __shared__ float pow95L[2049];
    __shared__ int   idxAllL[NTOK];
    __shared__ int   rankAllL[NTOK];
    __shared__ int   Mhist[NBLK * 32];
    __shared__ int   preL[NBLK * 32];
    __shared__ int   sufL[NBLK * 32];
    __shared__ float invntL[BLK];
    __shared__ int   MblkL[32];
    __shared__ float decayL[32];
    __shared__ int   offL[33];
    __shared__ int   listL[BLK];
    __shared__ float coefL[BLK];
    __shared__ int   segStartL[BLK];
    __shared__ int   segEndL[BLK];
    __shared__ int   MtotL[32];
    __shared__ int   globOffL[33];

    const int tid = threadIdx.x;
    const int w = tid >> 6;
    const int j = tid & 63;

    // 0.95^k table
    const float l295 = log2f(0.95f);
    for (int k = tid; k < 2049; k += 512) pow95L[k] = exp2f((float)k * l295);
    // block-0 column preload from D0
    for (int e = tid; e < BLK * 32; e += 512) {
        int i = e >> 5, s = e & 31;
        DblkL[i * 33 + s] = D[s * NTOK + i];
    }
    // block-0 G diagonal block into LDS
    for (int e = tid; e < BLK * (BLK / 4); e += 512) {
        int r = e >> 5, f = e & 31;
        *(float4*)&GdL[r * BLK + 4 * f] =
            *(const float4*)&G[(size_t)r * NTOK + 4 * f];
    }
    __syncthreads();

    // wave-0 persistent per-lane state: lane s owns slot s (s = j for j<32)
    float ssd = 0.0f, invns = 0.0f;
    unsigned emptyMask = 0;
    if (w == 0) {
        if (j < 32) {
            const float* sr = slots_in + j * DIM;
            float a = 0.0f;
#pragma unroll 4
            for (int d = 0; d < DIM; d += 4) {
                float4 v = *(const float4*)&sr[d];
                a = fmaf(v.x, v.x, a); a = fmaf(v.y, v.y, a);
                a = fmaf(v.z, v.z, a); a = fmaf(v.w, v.w, a);
            }
            ssd = a;
        }
        invns = 1.0f / fmaxf(sqrtf(ssd), COS_EPS);
        for (int s = 0; s < 32; ++s)
            if (usage_in[s] == 0.0f) emptyMask |= (1u << s);
    }

#pragma unroll 1
    for (int b = 0; b < NBLK; ++b) {
        const int t0 = b * BLK;
        // phase A: token inv-norms (from staged diag) + seg-mark init
        for (int i = tid; i < BLK; i += 512) {
            float g = GdL[i * BLK + i];
            invntL[i] = 1.0f / fmaxf(sqrtf(g), COS_EPS);
            segStartL[i] = -1;
            segEndL[i] = -1;
        }
        __syncthreads();

        if (w == 0) {
            int mcnt = 0;
            float dcolP = DblkL[(j & 31)];        // prefetch row 0
            int idxPrev = -1;
            float gcross = 0.0f;
#pragma unroll 1
            for (int i = 0; i < BLK; ++i) {
                // all LDS reads up front; dcolP was prefetched last iteration
                const float g0 = GdL[i * BLK + j];
                const float g1 = GdL[i * BLK + 64 + j];
                const float nt2 = GdL[i * BLK + i];
                const float invnt = invntL[i];
                // apply previous iteration's single-slot update in-register
                float dcol = dcolP;
                if ((j & 31) == idxPrev) dcol = fmaf(MOM, dcol, OMM * gcross);
                // prefetch next row BEFORE this iteration's writes
                dcolP = DblkL[(i + 1) * 33 + (j & 31)];
                gcross = GdL[i * BLK + (i + 1)];   // G[tok i][tok i+1], uniform

                int idx;
                if (emptyMask) {                   // uniform branch
                    idx = (int)__builtin_ctz(emptyMask);
                    emptyMask &= emptyMask - 1;
                } else {
                    float bv = dcol * invns * invnt;
                    int bi = j;
                    // lanes 32..63 hold garbage but no merge crosses into 0..31
                    argmax_dpp_step<0xB1>(bv, bi);    // quad_perm xor1
                    argmax_dpp_step<0x4E>(bv, bi);    // quad_perm xor2
                    argmax_dpp_step<0x124>(bv, bi);   // row_ror:4
                    argmax_dpp_step<0x128>(bv, bi);   // row_ror:8
                    argmax_dpp_step<0x142>(bv, bi);   // row_bcast15 -> lanes16..31
                    idx = __builtin_amdgcn_readlane(bi, 16);
                }

                if (j == idx) {                    // owning lane bookkeeping
                    rankAllL[t0 + i] = mcnt;
                    ++mcnt;
                    // ||.95a+.05b||^2 = .9025||a||^2 + .095 a.b + .0025||b||^2
                    ssd = MOM2 * ssd + MOMOMM2 * dcol + OMM2 * nt2;
                    invns = 1.0f / fmaxf(sqrtf(ssd), COS_EPS);
                }
                if (j == 0) idxAllL[t0 + i] = idx;
                // row-update future in-block columns (lane j owns rows j, 64+j)
                if (j > i) {
                    int a = j * 33 + idx;
                    DblkL[a] = fmaf(MOM, DblkL[a], OMM * g0);
                }
                {
                    int t2 = 64 + j;
                    if (t2 > i) {
                        int a = t2 * 33 + idx;
                        DblkL[a] = fmaf(MOM, DblkL[a], OMM * g1);
                    }
                }
                idxPrev = idx;
            }
            if (j < 32) {
                MblkL[j] = mcnt;
                Mhist[b * 32 + j] = mcnt;
                decayL[j] = pow95L[mcnt];
            }
            if (j == 0) {
                int o = 0;
                for (int s = 0; s < 32; ++s) { offL[s] = o; o += MblkL[s]; }
                offL[32] = o;
            }
        }
        __syncthreads();

        if (b < NBLK - 1) {
            // phase B: sorted per-slot lists + closed-form coefs + seg marks
            if (tid < BLK) {
                int sidx = idxAllL[t0 + tid];
                int r = rankAllL[t0 + tid];
                int p = offL[sidx] + r;
                listL[p] = tid;
                coefL[p] = OMM * pow95L[MblkL[sidx] - 1 - r];
            }
            if (tid < 32 && MblkL[tid] > 0) {
                segStartL[offL[tid]] = tid;
                segEndL[offL[tid + 1] - 1] = tid;
            }
            __syncthreads();

            // phase C: stage next G diag block + batched D column update
            const int t0n = t0 + BLK;
            for (int e = tid; e < BLK * (BLK / 4); e += 512) {
                int r = e >> 5, f = e & 31;
                *(float4*)&GdL[r * BLK + 4 * f] =
                    *(const float4*)&G[(size_t)(t0n + r) * NTOK + t0n + 4 * f];
            }
            const int tp = t0n + 4 * tid;
            if (tp < NTOK) {
                const bool toLds = (4 * tid) < BLK;
                float ax = 0.0f, ay = 0.0f, az = 0.0f, aw = 0.0f;
#pragma unroll 2
                for (int k = 0; k < BLK; ++k) {
                    int ss = segStartL[k];
                    if (ss >= 0) {
                        const float4 dv = *(const float4*)&D[ss * NTOK + tp];
                        const float de = decayL[ss];
                        ax = de * dv.x; ay = de * dv.y;
                        az = de * dv.z; aw = de * dv.w;
                    }
                    const int ii = listL[k];
                    const float c = coefL[k];
                    const float4 gv =
                        *(const float4*)&G[(size_t)(t0 + ii) * NTOK + tp];
                    ax = fmaf(c, gv.x, ax); ay = fmaf(c, gv.y, ay);
                    az = fmaf(c, gv.z, az); aw = fmaf(c, gv.w, aw);
                    int se = segEndL[k];
                    if (se >= 0) {
                        if (toLds) {
                            const int r0 = 4 * tid;
                            DblkL[(r0 + 0) * 33 + se] = ax;
                            DblkL[(r0 + 1) * 33 + se] = ay;
                            DblkL[(r0 + 2) * 33 + se] = az;
                            DblkL[(r0 + 3) * 33 + se] = aw;
                        } else {
                            float4 o; o.x = ax; o.y = ay; o.z = az; o.w = aw;
                            *(float4*)&D[se * NTOK + tp] = o;
                        }
                    }
                }
                if (toLds) {
                    // carry untouched slots into next-block staging
#pragma unroll 1
                    for (int s = 0; s < 32; ++s) {
                        if (MblkL[s] == 0) {
                            const float4 dv = *(const float4*)&D[s * NTOK + tp];
                            const int r0 = 4 * tid;
                            DblkL[(r0 + 0) * 33 + s] = dv.x;
                            DblkL[(r0 + 1) * 33 + s] = dv.y;
                            DblkL[(r0 + 2) * 33 + s] = dv.z;
                            DblkL[(r0 + 3) * 33 + s] = dv.w;
                        }
                    }
                }
            }
            __syncthreads();
        }
    }

    __syncthreads();
    // epilogue: global per-slot lists + coefs for slot materialization
    if (tid < 32) {
        int acc = 0;
        for (int bb = 0; bb < NBLK; ++bb) {
            preL[bb * 32 + tid] = acc;
            acc += Mhist[bb * 32 + tid];
        }
        MtotL[tid] = acc;
        int sacc = 0;
        for (int bb = NBLK - 1; bb >= 0; --bb) {
            sufL[bb * 32 + tid] = sacc;
            sacc += Mhist[bb * 32 + tid];
        }
    }
    __syncthreads();
    if (tid == 0) {
        int o = 0;
        for (int s = 0; s < 32; ++s) { globOffL[s] = o; o += MtotL[s]; }
        globOffL[32] = o;
    }
    __syncthreads();
    if (tid < 33) offG[tid] = globOffL[tid];
    if (tid < 32) {
        decayTotG[tid] = pow95L[MtotL[tid]];
        nsG[tid] = sqrtf(ssd);     // tid<32 ARE wave-0 lanes 0..31
    }
    for (int t = tid; t < NTOK; t += 512) {
        const int s = idxAllL[t];
        const int bb = t >> 7;
        const int r = rankAllL[t];
        const int pos = globOffL[s] + preL[bb * 32 + s] + r;
        const int e = (Mhist[bb * 32 + s] - 1 - r) + sufL[bb * 32 + s];
        listG[pos] = t;
        coefG[pos] = OMM * pow95L[e];
    }
}

// Materialize normalized slots: sn[s] = (0.95^M * slots0[s] + sum coef*tok)/ns
__global__ __launch_bounds__(256, 1) void mat_kernel(
    const float* __restrict__ wb, const float* __restrict__ slots_in,
    const float* __restrict__ coefG, const int* __restrict__ listG,
    const int* __restrict__ offG, const float* __restrict__ decayTotG,
    const float* __restrict__ nsG, float* __restrict__ sn)
{
    const int s = blockIdx.x >> 2;
    const int d = (blockIdx.x & 3) * 256 + threadIdx.x;
    float acc = decayTotG[s] * slots_in[s * DIM + d];
    const int k1 = offG[s + 1];
    for (int k = offG[s]; k < k1; ++k) {
        const int t = listG[k];
        acc = fmaf(coefG[k], wb[(size_t)t * DIM + d], acc);
    }
    sn[s * DIM + d] = acc * (1.0f / fmaxf(nsG[s], NORM_EPS));
}

// ===========================================================================
// OLD PATH (fallback if workspace is too small for G) — unchanged
// ===========================================================================

#define UPDATE_SLOT(i) { _Pragma("unroll") \
    for (int k = 0; k < 16; ++k) sreg[i][k] = MOM * sreg[i][k] + OMM * tv[k]; }

__global__ __launch_bounds__(256, 1) void scan_seq_kernel(
    const float* __restrict__ wb,
    const float* __restrict__ slots_in,
    const float* __restrict__ usage_in,
    float* __restrict__ sn_out,
    float* __restrict__ ns_out)
{
    const int tid = threadIdx.x;
    const int w = tid >> 6;
    const int j = tid & 63;

    __shared__ __align__(16) float tokL[DIM];
    __shared__ float ntp[4];
    __shared__ float simsL[NSLOTS];

    float sreg[8][16];
#pragma unroll
    for (int i = 0; i < 8; ++i) {
        const int s = 8 * w + i;
#pragma unroll
        for (int q = 0; q < 4; ++q) {
            float4 v = *(const float4*)&slots_in[s * DIM + 256 * q + 4 * j];
            sreg[i][4*q+0] = v.x; sreg[i][4*q+1] = v.y;
            sreg[i][4*q+2] = v.z; sreg[i][4*q+3] = v.w;
        }
    }
    float ssd;
    {
        float v[8];
#pragma unroll
        for (int i = 0; i < 8; ++i) {
            float a = 0.0f;
#pragma unroll
            for (int k = 0; k < 16; ++k) a = fmaf(sreg[i][k], sreg[i][k], a);
            v[i] = a;
        }
        ssd = reduce8(v, j);
    }
    unsigned emptyMask = 0;
    for (int s = 0; s < NSLOTS; ++s)
        if (usage_in[s] == 0.0f) emptyMask |= (1u << s);

    float4 gA = *(const float4*)&wb[0 * DIM + 4 * tid];
    float4 gB = *(const float4*)&wb[1 * DIM + 4 * tid];

#pragma unroll 1
    for (int t = 0; t < NTOK; ++t) {
        const float4 gc = gA;
        gA = gB;
        if (t + 2 < NTOK) gB = *(const float4*)&wb[(t + 2) * DIM + 4 * tid];

        *(float4*)&tokL[4 * tid] = gc;
        float s2 = gc.x*gc.x + gc.y*gc.y + gc.z*gc.z + gc.w*gc.w;
        s2 = reduce_all(s2);
        if (j == 0) ntp[w] = s2;
        __syncthreads();

        const float nt2 = ntp[0] + ntp[1] + ntp[2] + ntp[3];
        const float invnt = 1.0f / fmaxf(sqrtf(nt2), COS_EPS);

        float tv[16];
#pragma unroll
        for (int q = 0; q < 4; ++q) {
            float4 tq = *(const float4*)&tokL[256 * q + 4 * j];
            tv[4*q+0] = tq.x; tv[4*q+1] = tq.y; tv[4*q+2] = tq.z; tv[4*q+3] = tq.w;
        }
        float vv[8];
#pragma unroll
        for (int i = 0; i < 8; ++i) {
            float a = 0.0f;
#pragma unroll
            for (int k = 0; k < 16; ++k) a = fmaf(sreg[i][k], tv[k], a);
            vv[i] = a;
        }
        const float dotd = reduce8(vv, j);
        const float invd = 1.0f / fmaxf(sqrtf(ssd), COS_EPS);
        if ((j & 7) == 0) simsL[8 * w + (j >> 3)] = dotd * invd * invnt;
        __syncthreads();

        int idx;
        if (emptyMask) {
            idx = (int)__builtin_ctz(emptyMask);
            emptyMask &= ~(1u << idx);
        } else {
            float bv = simsL[j & 31];
            int bi = j & 31;
#pragma unroll
            for (int m = 1; m < 64; m <<= 1) {
                float ov = __shfl_xor(bv, m, 64);
                int   oi = __shfl_xor(bi, m, 64);
                if (ov > bv || (ov == bv && oi < bi)) { bv = ov; bi = oi; }
            }
            idx = bi;
        }

        if ((idx >> 3) == w) {
            switch (idx & 7) {
                case 0: UPDATE_SLOT(0); break;
                case 1: UPDATE_SLOT(1); break;
                case 2: UPDATE_SLOT(2); break;
                case 3: UPDATE_SLOT(3); break;
                case 4: UPDATE_SLOT(4); break;
                case 5: UPDATE_SLOT(5); break;
                case 6: UPDATE_SLOT(6); break;
                case 7: UPDATE_SLOT(7); break;
            }
            if ((j >> 3) == (idx & 7))
                ssd = MOM2 * ssd + MOMOMM2 * dotd + OMM2 * nt2;
        }
    }

    const float nsv = sqrtf(ssd);
    if ((j & 7) == 0) ns_out[8 * w + (j >> 3)] = nsv;
#pragma unroll
    for (int i = 0; i < 8; ++i) {
        const float ns_i = __shfl(nsv, i << 3, 64);
        const float inv_i = 1.0f / fmaxf(ns_i, NORM_EPS);
        const int s = 8 * w + i;
#pragma unroll
        for (int q = 0; q < 4; ++q) {
            float4 o;
            o.x = sreg[i][4*q+0] * inv_i;
            o.y = sreg[i][4*q+1] * inv_i;
            o.z = sreg[i][4*q+2] * inv_i;
            o.w = sreg[i][4*q+3] * inv_i;
            *(float4*)&sn_out[s * DIM + 256 * q + 4 * j] = o;
        }
    }
}

// ---------------------------------------------------------------------------
// Retrieve: unchanged.
// ---------------------------------------------------------------------------
__global__ __launch_bounds__(512, 2) void retrieve_kernel(
    const float* __restrict__ x,
    const float* __restrict__ sn_g,
    const float* __restrict__ ns_g,
    float* __restrict__ out)
{
    __shared__ __align__(16) float snL[8 * DIM];
    __shared__ float nsL[NSLOTS];
    __shared__ __align__(16) float scL[8 * 4 * NSLOTS];

    const int tid = threadIdx.x;
    const int w = tid >> 6;
    const int j = tid & 63;

    if (tid < NSLOTS) nsL[tid] = ns_g[tid];

    const int rowbase = (blockIdx.x * 8 + w) * 4;

    float xv[4][16];
#pragma unroll
    for (int r = 0; r < 4; ++r) {
        const float* xr = &x[(long)(rowbase + r) * DIM];
#pragma unroll
        for (int q = 0; q < 4; ++q) {
            float4 v = *(const float4*)&xr[256 * q + 4 * j];
            xv[r][4*q+0] = v.x; xv[r][4*q+1] = v.y;
            xv[r][4*q+2] = v.z; xv[r][4*q+3] = v.w;
        }
    }
    float mul[4];
#pragma unroll
    for (int r = 0; r < 4; ++r) {
        float a = 0.0f;
#pragma unroll
        for (int k = 0; k < 16; ++k) a = fmaf(xv[r][k], xv[r][k], a);
        a = reduce_all(a);
        mul[r] = (1.0f / fmaxf(sqrtf(a), NORM_EPS)) * INV_TEMP;
    }

#pragma unroll 1
    for (int h = 0; h < 4; ++h) {
        if (h) __syncthreads();
        for (int i = tid; i < 8 * DIM / 4; i += 512)
            *(float4*)&snL[4 * i] = *(const float4*)&sn_g[h * 8 * DIM + 4 * i];
        __syncthreads();
#pragma unroll 1
        for (int si = 0; si < 8; ++si) {
            const int s = 8 * h + si;
            float snv[16];
#pragma unroll
            for (int q = 0; q < 4; ++q) {
                float4 v = *(const float4*)&snL[si * DIM + 256 * q + 4 * j];
                snv[4*q+0]=v.x; snv[4*q+1]=v.y; snv[4*q+2]=v.z; snv[4*q+3]=v.w;
            }
            float p[4];
#pragma unroll
            for (int r = 0; r < 4; ++r) {
                float a = 0.0f;
#pragma unroll
                for (int k = 0; k < 16; ++k) a = fmaf(xv[r][k], snv[k], a);
                p[r] = a;
            }
            float d = reduce4(p, j);
            if ((j & 15) == 0) scL[w * 128 + (j >> 4) * 32 + s] = d;
        }
    }

    {
        const int r = j & 3;
        const float mulr = (r == 0) ? mul[0] : (r == 1) ? mul[1]
                         : (r == 2) ? mul[2] : mul[3];
        float sc[32];
#pragma unroll
        for (int s4 = 0; s4 < 8; ++s4) {
            float4 v = *(const float4*)&scL[w * 128 + r * 32 + 4 * s4];
            sc[4*s4+0]=v.x; sc[4*s4+1]=v.y; sc[4*s4+2]=v.z; sc[4*s4+3]=v.w;
        }
        float m = -INFINITY;
#pragma unroll
        for (int s = 0; s < 32; ++s) { sc[s] *= mulr; m = fmaxf(m, sc[s]); }
        float sum = 0.0f;
#pragma unroll
        for (int s = 0; s < 32; ++s) { sc[s] = expf(sc[s] - m); sum += sc[s]; }
        const float isum = 1.0f / sum;
        if (j < 4) {
#pragma unroll
            for (int s4 = 0; s4 < 8; ++s4) {
                float4 o;
                o.x = sc[4*s4+0] * isum * nsL[4*s4+0];
                o.y = sc[4*s4+1] * isum * nsL[4*s4+1];
                o.z = sc[4*s4+2] * isum * nsL[4*s4+2];
                o.w = sc[4*s4+3] * isum * nsL[4*s4+3];
                *(float4*)&scL[w * 128 + j * 32 + 4 * s4] = o;
            }
        }
    }

    float acc[4][16];
#pragma unroll
    for (int r = 0; r < 4; ++r)
#pragma unroll
        for (int k = 0; k < 16; ++k) acc[r][k] = 0.0f;

#pragma unroll 1
    for (int h = 3; h >= 0; --h) {
        if (h != 3) {
            __syncthreads();
            for (int i = tid; i < 8 * DIM / 4; i += 512)
                *(float4*)&snL[4 * i] = *(const float4*)&sn_g[h * 8 * DIM + 4 * i];
            __syncthreads();
        }
#pragma unroll 1
        for (int si = 0; si < 8; ++si) {
            const int s = 8 * h + si;
            float snv[16];
#pragma unroll
            for (int q = 0; q < 4; ++q) {
                float4 v = *(const float4*)&snL[si * DIM + 256 * q + 4 * j];
                snv[4*q+0]=v.x; snv[4*q+1]=v.y; snv[4*q+2]=v.z; snv[4*q+3]=v.w;
            }
#pragma unroll
            for (int r = 0; r < 4; ++r) {
                const float ww = scL[w * 128 + r * 32 + s];
#pragma unroll
                for (int k = 0; k < 16; ++k) acc[r][k] = fmaf(ww, snv[k], acc[r][k]);
            }
        }
    }

#pragma unroll
    for (int r = 0; r < 4; ++r) {
        float* orow = &out[(long)(rowbase + r) * DIM];
#pragma unroll
        for (int q = 0; q < 4; ++q) {
            float4 o;
            o.x = acc[r][4*q+0]; o.y = acc[r][4*q+1];
            o.z = acc[r][4*q+2]; o.w = acc[r][4*q+3];
            *(float4*)&orow[256 * q + 4 * j] = o;
        }
    }
}

extern "C" void kernel_launch(void* const* d_in, const int* in_sizes, int n_in,
                              void* d_out, int out_size, void* d_ws, size_t ws_size,
                              hipStream_t stream) {
    const float* x  = (const float*)d_in[0];   // [4,8192,1024]
    const float* wb = (const float*)d_in[1];   // [2048,1024]
    const float* sl = (const float*)d_in[2];   // [32,1024]
    const float* us = (const float*)d_in[3];   // [32]
    float* out = (float*)d_out;

    // workspace layout (floats)
    float* sn   = (float*)d_ws;                    // 32*1024
    float* nsG  = sn + NSLOTS * DIM;               // 32 (pad 64)
    float* D    = nsG + 64;                        // 32*2048
    float* G    = D + NSLOTS * NTOK;               // 2048*2048
    float* coefG = G + (size_t)NTOK * NTOK;        // 2048
    int* listG  = (int*)(coefG + NTOK);            // 2048
    int* offG   = listG + NTOK;                    // 33 (pad 64)
    float* decayTotG = (float*)(offG + 64);        // 32
    const size_t ws_need = (size_t)((decayTotG + 64) - sn) * sizeof(float);

    if (ws_size >= ws_need) {
        gram_kernel<<<dim3(136 * 4), dim3(256), 0, stream>>>(wb, G);
        slotdot_kernel<<<dim3(256), dim3(256), 0, stream>>>(wb, sl, D);
        scan_kernel<<<dim3(1), dim3(512), 0, stream>>>(
            sl, us, G, D, listG, coefG, offG, decayTotG, nsG);
        mat_kernel<<<dim3(128), dim3(256), 0, stream>>>(
            wb, sl, coefG, listG, offG, decayTotG, nsG, sn);
    } else {
        // fallback: proven sequential path
        scan_seq_kernel<<<dim3(1), dim3(256), 0, stream>>>(wb, sl, us, sn, nsG);
    }
    retrieve_kernel<<<dim3(NROWS / 32), dim3(512), 0, stream>>>(x, sn, nsG, out);
}

// Round 3
// 1881.531 us; speedup vs baseline: 2.5283x; 1.3297x over previous
//
#include <hip/hip_runtime.h>
#include <math.h>

#define NSLOTS 32
#define DIM    1024
#define NTOK   2048
#define NROWS  32768
#define NBLK   16
#define BLK    128

#define MOM      0.95f
#define OMM      0.05f
#define MOM2     0.9025f   // 0.95^2
#define MOMOMM2  0.095f    // 2*0.95*0.05
#define OMM2     0.0025f   // 0.05^2
#define INV_TEMP (1.0f/0.35f)
#define COS_EPS  1e-8f
#define NORM_EPS 1e-12f

__device__ __forceinline__ float reduce_all(float v) {
    v += __shfl_xor(v, 32, 64);
    v += __shfl_xor(v, 16, 64);
    v += __shfl_xor(v, 8, 64);
    v += __shfl_xor(v, 4, 64);
    v += __shfl_xor(v, 2, 64);
    v += __shfl_xor(v, 1, 64);
    return v;
}

// 8-value halving butterfly over 64 lanes (fallback path).
__device__ __forceinline__ float reduce8(const float v[8], int lane) {
    const bool b5 = (lane & 32) != 0;
    const bool b4 = (lane & 16) != 0;
    const bool b3 = (lane & 8) != 0;
    float t[4];
#pragma unroll
    for (int k = 0; k < 4; ++k) {
        float send = b5 ? v[k] : v[k + 4];
        float recv = __shfl_xor(send, 32, 64);
        t[k] = (b5 ? v[k + 4] : v[k]) + recv;
    }
    float u[2];
#pragma unroll
    for (int k = 0; k < 2; ++k) {
        float send = b4 ? t[k] : t[k + 2];
        float recv = __shfl_xor(send, 16, 64);
        u[k] = (b4 ? t[k + 2] : t[k]) + recv;
    }
    float send = b3 ? u[0] : u[1];
    float recv = __shfl_xor(send, 8, 64);
    float r = (b3 ? u[1] : u[0]) + recv;
    r += __shfl_xor(r, 4, 64);
    r += __shfl_xor(r, 2, 64);
    r += __shfl_xor(r, 1, 64);
    return r;
}

// 4-value variant; result for r = (lane>>4)&3, shared by all 16 lanes of group.
__device__ __forceinline__ float reduce4(const float v[4], int lane) {
    const bool b5 = (lane & 32) != 0;
    const bool b4 = (lane & 16) != 0;
    float t[2];
#pragma unroll
    for (int k = 0; k < 2; ++k) {
        float send = b5 ? v[k] : v[k + 2];
        float recv = __shfl_xor(send, 32, 64);
        t[k] = (b5 ? v[k + 2] : v[k]) + recv;
    }
    float send = b4 ? t[0] : t[1];
    float recv = __shfl_xor(send, 16, 64);
    float r = (b4 ? t[1] : t[0]) + recv;
    r += __shfl_xor(r, 8, 64);
    r += __shfl_xor(r, 4, 64);
    r += __shfl_xor(r, 2, 64);
    r += __shfl_xor(r, 1, 64);
    return r;
}

template<int C>
__device__ __forceinline__ float max_dpp(float v) {
    float o = __int_as_float(__builtin_amdgcn_update_dpp(
        __float_as_int(v), __float_as_int(v), C, 0xf, 0xf, true));
    return fmaxf(v, o);
}

// ===========================================================================
// NEW PATH
// ===========================================================================

// G upper-triangle blocks: grid = 136 pairs * 4 i-quarters = 544 wgs, 256 thr.
#define GKC 64
__global__ __launch_bounds__(256, 1) void gram_kernel(
    const float* __restrict__ wb, float* __restrict__ G)
{
    __shared__ float As[GKC * 36];
    __shared__ float Bs[GKC * 132];

    int p = blockIdx.x >> 2, iq = blockIdx.x & 3;
    int bi = 0, base = 0;
    while (p >= base + (NBLK - bi)) { base += NBLK - bi; ++bi; }
    const int bj = bi + (p - base);
    const int arow = bi * BLK + iq * 32;
    const int brow = bj * BLK;
    const int tid = threadIdx.x;
    const int jl = tid & 127;
    const int ih = tid >> 7;

    float acc[16];
#pragma unroll
    for (int c = 0; c < 16; ++c) acc[c] = 0.0f;

#pragma unroll 1
    for (int kc = 0; kc < DIM; kc += GKC) {
        __syncthreads();
        for (int v = tid; v < 32 * GKC / 4; v += 256) {
            int row = v >> 4, f = v & 15;
            float4 x = *(const float4*)&wb[(size_t)(arow + row) * DIM + kc + 4 * f];
            As[(4 * f + 0) * 36 + row] = x.x;
            As[(4 * f + 1) * 36 + row] = x.y;
            As[(4 * f + 2) * 36 + row] = x.z;
            As[(4 * f + 3) * 36 + row] = x.w;
        }
        for (int v = tid; v < 128 * GKC / 4; v += 256) {
            int row = v >> 4, f = v & 15;
            float4 x = *(const float4*)&wb[(size_t)(brow + row) * DIM + kc + 4 * f];
            Bs[(4 * f + 0) * 132 + row] = x.x;
            Bs[(4 * f + 1) * 132 + row] = x.y;
            Bs[(4 * f + 2) * 132 + row] = x.z;
            Bs[(4 * f + 3) * 132 + row] = x.w;
        }
        __syncthreads();
#pragma unroll 1
        for (int k = 0; k < GKC; ++k) {
            float bv = Bs[k * 132 + jl];
            const float4* ap = (const float4*)&As[k * 36 + ih * 16];
            float4 A0 = ap[0], A1 = ap[1], A2 = ap[2], A3 = ap[3];
            acc[0]  = fmaf(A0.x, bv, acc[0]);
            acc[1]  = fmaf(A0.y, bv, acc[1]);
            acc[2]  = fmaf(A0.z, bv, acc[2]);
            acc[3]  = fmaf(A0.w, bv, acc[3]);
            acc[4]  = fmaf(A1.x, bv, acc[4]);
            acc[5]  = fmaf(A1.y, bv, acc[5]);
            acc[6]  = fmaf(A1.z, bv, acc[6]);
            acc[7]  = fmaf(A1.w, bv, acc[7]);
            acc[8]  = fmaf(A2.x, bv, acc[8]);
            acc[9]  = fmaf(A2.y, bv, acc[9]);
            acc[10] = fmaf(A2.z, bv, acc[10]);
            acc[11] = fmaf(A2.w, bv, acc[11]);
            acc[12] = fmaf(A3.x, bv, acc[12]);
            acc[13] = fmaf(A3.y, bv, acc[13]);
            acc[14] = fmaf(A3.z, bv, acc[14]);
            acc[15] = fmaf(A3.w, bv, acc[15]);
        }
    }
#pragma unroll
    for (int c = 0; c < 16; ++c) {
        int i = arow + ih * 16 + c;
        G[(size_t)i * NTOK + brow + jl] = acc[c];
    }
}

// D0[s][t] = dot(slots0[s], wb[t]); grid = 256 wgs * 256 thr (8 tokens each)
__global__ __launch_bounds__(256, 1) void slotdot_kernel(
    const float* __restrict__ wb, const float* __restrict__ slots_in,
    float* __restrict__ D)
{
    __shared__ float tokL[8 * DIM];
    const int tid = threadIdx.x;
    const int t0 = blockIdx.x * 8;
    for (int v = tid; v < 8 * DIM / 4; v += 256)
        *(float4*)&tokL[4 * v] = *(const float4*)&wb[(size_t)t0 * DIM + 4 * v];
    __syncthreads();
    const int s = tid & 31, tl = tid >> 5;
    const float* sp = slots_in + s * DIM;
    const float* tp = tokL + tl * DIM;
    float acc = 0.0f;
    for (int d = 0; d < DIM; d += 4) {
        float4 a = *(const float4*)&sp[d];
        float4 t = *(const float4*)&tp[d];
        acc = fmaf(a.x, t.x, acc); acc = fmaf(a.y, t.y, acc);
        acc = fmaf(a.z, t.z, acc); acc = fmaf(a.w, t.w, acc);
    }
    D[s * NTOK + t0 + tl] = acc;
}

// ---------------------------------------------------------------------------
// Sequential routing scan, Gram form. 1 block x 512 threads.
// The recurrence is LDS-free: all operands prefetched into registers >=1
// iteration ahead; pending D updates applied via an in-register fix chain.
// Arithmetic sequence is bit-identical to the previous (passing) version.
// ---------------------------------------------------------------------------
__global__ __launch_bounds__(512, 1) void scan_kernel(
    const float* __restrict__ slots_in,
    const float* __restrict__ usage_in,
    const float* __restrict__ G,
    float* __restrict__ D,
    int* __restrict__ listG,
    float* __restrict__ coefG,
    int* __restrict__ offG,
    float* __restrict__ decayTotG,
    float* __restrict__ nsG)
{
    __shared__ float GdL[BLK * BLK];        // 64KB staged diag block of G
    __shared__ float DblkL[BLK * 33];       // [row][slot], col 32 = dump
    __shared__ float pow95L[2049];
    __shared__ int   idxAllL[NTOK];
    __shared__ int   rankAllL[NTOK];
    __shared__ int   Mhist[NBLK * 32];
    __shared__ int   preL[NBLK * 32];
    __shared__ int   sufL[NBLK * 32];
    __shared__ int   MblkL[32];
    __shared__ float decayL[32];
    __shared__ int   offL[33];
    __shared__ int   pkIdxL[BLK];
    __shared__ float pkCoefL[BLK];
    __shared__ int   MtotL[32];
    __shared__ int   globOffL[33];

    const int tid = threadIdx.x;
    const int w = tid >> 6;
    const int j = tid & 63;
    const int js = j & 31;

    // 0.95^k table
    const float l295 = log2f(0.95f);
    for (int k = tid; k < 2049; k += 512) pow95L[k] = exp2f((float)k * l295);
    // block-0 column preload from D0
    for (int e = tid; e < BLK * 32; e += 512) {
        int i = e >> 5, s = e & 31;
        DblkL[i * 33 + s] = D[s * NTOK + i];
    }
    // block-0 G diagonal block into LDS
    for (int e = tid; e < BLK * (BLK / 4); e += 512) {
        int r = e >> 5, f = e & 31;
        *(float4*)&GdL[r * BLK + 4 * f] =
            *(const float4*)&G[(size_t)r * NTOK + 4 * f];
    }
    __syncthreads();

    // wave-0 persistent per-lane state: lane s owns slot s (s = j for j<32)
    float ssd = 0.0f, invns = 0.0f;
    unsigned emptyMask = 0;
    if (w == 0) {
        if (j < 32) {
            const float* sr = slots_in + j * DIM;
            float a = 0.0f;
#pragma unroll 4
            for (int d = 0; d < DIM; d += 4) {
                float4 v = *(const float4*)&sr[d];
                a = fmaf(v.x, v.x, a); a = fmaf(v.y, v.y, a);
                a = fmaf(v.z, v.z, a); a = fmaf(v.w, v.w, a);
            }
            ssd = a;
            invns = 1.0f / fmaxf(sqrtf(ssd), COS_EPS);
        }
        for (int s = 0; s < 32; ++s)
            if (usage_in[s] == 0.0f) emptyMask |= (1u << s);
    }

#pragma unroll 1
    for (int b = 0; b < NBLK; ++b) {
        const int t0 = b * BLK;

        if (w == 0) {
            int mcnt = 0;
            // ---- warmup: register pipelines ----
            float dr0 = DblkL[0 * 33 + js];           // row i
            float dr1 = DblkL[1 * 33 + js];           // row i+1
            float dr2 = DblkL[2 * 33 + js];           // row i+2
            float nt2c = GdL[0];                      // G[0][0]
            float nt2n = GdL[1 * BLK + 1];            // G[1][1]
            float invntc = 1.0f / fmaxf(sqrtf(nt2c), COS_EPS);
            float invntn = 1.0f / fmaxf(sqrtf(nt2n), COS_EPS);
            float gAc = 0.0f, gBc = 0.0f, gCc = 0.0f; // fix G values for iter i
            float m3 = 1.0f, m2 = 1.0f, m1 = 1.0f;    // fix mult pipeline
            float a3 = 0.0f, a2 = 0.0f, a1 = 0.0f;    // fix add-coef pipeline
            float g0P = 0.0f, g1P = 0.0f;             // G[i-1][j], G[i-1][64+j]
            float pv0 = 0.0f, pv1 = 0.0f;             // pending RMW values
            int   pa0 = 0, pa1 = 0;                   // pending RMW addrs
            int   sIdx = 0;

#pragma unroll 1
            for (int i = 0; i < BLK; ++i) {
                // ---- deferred RMW write for m = i-1 (before prefetches) ----
                if (i) {
                    DblkL[pa0] = fmaf(MOM, pv0, OMM * g0P);
                    DblkL[pa1] = fmaf(MOM, pv1, OMM * g1P);
                }
                // ---- prefetch issues (all >=1 iteration ahead) ----
                float drN = DblkL[min(i + 3, BLK - 1) * 33 + js];
                int tf = min(i + 1, BLK - 1);
                float gAn = GdL[max(tf - 3, 0) * BLK + tf];
                float gBn = GdL[max(tf - 2, 0) * BLK + tf];
                float gCn = GdL[max(tf - 1, 0) * BLK + tf];
                int tn = min(i + 2, BLK - 1);
                float nt2in = GdL[tn * BLK + tn];
                float g0n = GdL[i * BLK + j];
                float g1n = GdL[i * BLK + 64 + j];

                // ---- fix chain: apply pending m=i-3,i-2,i-1 in order ----
                float dcol = dr0;
                dcol = fmaf(m3, dcol, a3 * gAc);
                dcol = fmaf(m2, dcol, a2 * gBc);
                dcol = fmaf(m1, dcol, a1 * gCc);

                // ---- select idx ----
                if (emptyMask) {                      // uniform branch
                    sIdx = (int)__builtin_ctz(emptyMask);
                    emptyMask &= emptyMask - 1;
                } else {
                    float bv = dcol * invns * invntc;
                    float mv = bv;
                    mv = max_dpp<0xB1>(mv);           // quad_perm xor1
                    mv = max_dpp<0x4E>(mv);           // quad_perm xor2
                    mv = max_dpp<0x124>(mv);          // row_ror:4
                    mv = max_dpp<0x128>(mv);          // row_ror:8
                    mv = max_dpp<0x142>(mv);          // row_bcast15
                    float smax = __int_as_float(
                        __builtin_amdgcn_readlane(__float_as_int(mv), 16));
                    unsigned long long bm = __ballot(bv == smax);
                    sIdx = (int)__builtin_ctzll(bm);
                }

                // ---- owning lane bookkeeping ----
                if (j == sIdx) {
                    rankAllL[t0 + i] = mcnt;
                    idxAllL[t0 + i] = sIdx;
                    ++mcnt;
                    // ||.95a+.05b||^2 = .9025||a||^2 + .095 a.b + .0025||b||^2
                    ssd = MOM2 * ssd + MOMOMM2 * dcol + OMM2 * nt2c;
                    invns = 1.0f / fmaxf(sqrtf(ssd), COS_EPS);
                }

                // ---- issue next pending RMW reads (rows > i+3, else dump) ----
                {
                    int c0 = (j > i + 3) ? sIdx : 32;
                    int c1 = ((64 + j) > i + 3) ? sIdx : 32;
                    pa0 = j * 33 + c0;
                    pa1 = (64 + j) * 33 + c1;
                    pv0 = DblkL[pa0];
                    pv1 = DblkL[pa1];
                }

                // ---- shift pipelines ----
                m3 = m2; a3 = a2; m2 = m1; a2 = a1;
                {
                    bool c = (js == sIdx);
                    m1 = c ? MOM : 1.0f;
                    a1 = c ? OMM : 0.0f;
                }
                gAc = gAn; gBc = gBn; gCc = gCn;
                invntc = invntn;
                nt2c = nt2n; nt2n = nt2in;
                invntn = 1.0f / fmaxf(sqrtf(nt2in), COS_EPS);
                dr0 = dr1; dr1 = dr2; dr2 = drN;
                g0P = g0n; g1P = g1n;
            }
            if (j < 32) {
                MblkL[j] = mcnt;
                Mhist[b * 32 + j] = mcnt;
                decayL[j] = pow95L[mcnt];
            }
            if (j == 0) {
                int o = 0;
                for (int s = 0; s < 32; ++s) { offL[s] = o; o += MblkL[s]; }
                offL[32] = o;
            }
        }
        __syncthreads();

        if (b < NBLK - 1) {
            // phase B: packed per-slot lists (flags computed locally)
            if (tid < BLK) {
                int sidx = idxAllL[t0 + tid];
                int r = rankAllL[t0 + tid];
                int mb = MblkL[sidx];
                int p = offL[sidx] + r;
                pkIdxL[p] = tid | ((r == 0 ? sidx + 1 : 0) << 12)
                                | ((r == mb - 1 ? sidx + 1 : 0) << 18);
                pkCoefL[p] = OMM * pow95L[mb - 1 - r];
            }
            __syncthreads();

            // phase C: stage next G diag block + batched D column update
            const int t0n = t0 + BLK;
            for (int e = tid; e < BLK * (BLK / 4); e += 512) {
                int r = e >> 5, f = e & 31;
                *(float4*)&GdL[r * BLK + 4 * f] =
                    *(const float4*)&G[(size_t)(t0n + r) * NTOK + t0n + 4 * f];
            }
            const int tp = t0n + 4 * tid;
            if (tp < NTOK) {
                const bool toLds = (4 * tid) < BLK;
                const int r0 = 4 * tid;
                if (toLds) {
                    // preload next block's DblkL with current D (all slots);
                    // assigned slots get overwritten at their segEnd below.
#pragma unroll 1
                    for (int s = 0; s < 32; ++s) {
                        float4 dv = *(const float4*)&D[(size_t)s * NTOK + tp];
                        DblkL[(r0 + 0) * 33 + s] = dv.x;
                        DblkL[(r0 + 1) * 33 + s] = dv.y;
                        DblkL[(r0 + 2) * 33 + s] = dv.z;
                        DblkL[(r0 + 3) * 33 + s] = dv.w;
                    }
                }
                float4 acc; acc.x = acc.y = acc.z = acc.w = 0.0f;
#pragma unroll 1
                for (int kk = 0; kk < BLK; kk += 8) {
                    int pi[8]; float pc[8];
#pragma unroll
                    for (int u = 0; u < 8; ++u) {
                        pi[u] = pkIdxL[kk + u];
                        pc[u] = pkCoefL[kk + u];
                    }
                    float4 gv[8];
#pragma unroll
                    for (int u = 0; u < 8; ++u) {
                        int ii = pi[u] & 0xFFF;
                        gv[u] = *(const float4*)&G[(size_t)(t0 + ii) * NTOK + tp];
                    }
                    float4 dv[8]; float de[8];
#pragma unroll
                    for (int u = 0; u < 8; ++u) {
                        int ss = ((pi[u] >> 12) & 63) - 1;
                        if (ss >= 0) {
                            dv[u] = *(const float4*)&D[(size_t)ss * NTOK + tp];
                            de[u] = decayL[ss];
                        } else {
                            dv[u].x = dv[u].y = dv[u].z = dv[u].w = 0.0f;
                            de[u] = 0.0f;
                        }
                    }
#pragma unroll
                    for (int u = 0; u < 8; ++u) {
                        int ss = ((pi[u] >> 12) & 63) - 1;
                        int se = ((pi[u] >> 18) & 63) - 1;
                        if (ss >= 0) {
                            acc.x = de[u] * dv[u].x;
                            acc.y = de[u] * dv[u].y;
                            acc.z = de[u] * dv[u].z;
                            acc.w = de[u] * dv[u].w;
                        }
                        acc.x = fmaf(pc[u], gv[u].x, acc.x);
                        acc.y = fmaf(pc[u], gv[u].y, acc.y);
                        acc.z = fmaf(pc[u], gv[u].z, acc.z);
                        acc.w = fmaf(pc[u], gv[u].w, acc.w);
                        if (se >= 0) {
                            if (toLds) {
                                DblkL[(r0 + 0) * 33 + se] = acc.x;
                                DblkL[(r0 + 1) * 33 + se] = acc.y;
                                DblkL[(r0 + 2) * 33 + se] = acc.z;
                                DblkL[(r0 + 3) * 33 + se] = acc.w;
                            } else {
                                *(float4*)&D[(size_t)se * NTOK + tp] = acc;
                            }
                        }
                    }
                }
            }
            __syncthreads();
        }
    }

    __syncthreads();
    // epilogue: global per-slot lists + coefs for slot materialization
    if (tid < 32) {
        int acc = 0;
        for (int bb = 0; bb < NBLK; ++bb) {
            preL[bb * 32 + tid] = acc;
            acc += Mhist[bb * 32 + tid];
        }
        MtotL[tid] = acc;
        int sacc = 0;
        for (int bb = NBLK - 1; bb >= 0; --bb) {
            sufL[bb * 32 + tid] = sacc;
            sacc += Mhist[bb * 32 + tid];
        }
    }
    __syncthreads();
    if (tid == 0) {
        int o = 0;
        for (int s = 0; s < 32; ++s) { globOffL[s] = o; o += MtotL[s]; }
        globOffL[32] = o;
    }
    __syncthreads();
    if (tid < 33) offG[tid] = globOffL[tid];
    if (tid < 32) {
        decayTotG[tid] = pow95L[MtotL[tid]];
        nsG[tid] = sqrtf(ssd);     // tid<32 ARE wave-0 lanes 0..31
    }
    for (int t = tid; t < NTOK; t += 512) {
        const int s = idxAllL[t];
        const int bb = t >> 7;
        const int r = rankAllL[t];
        const int pos = globOffL[s] + preL[bb * 32 + s] + r;
        const int e = (Mhist[bb * 32 + s] - 1 - r) + sufL[bb * 32 + s];
        listG[pos] = t;
        coefG[pos] = OMM * pow95L[e];
    }
}

// Materialize normalized slots: sn[s] = (0.95^M * slots0[s] + sum coef*tok)/ns
__global__ __launch_bounds__(256, 1) void mat_kernel(
    const float* __restrict__ wb, const float* __restrict__ slots_in,
    const float* __restrict__ coefG, const int* __restrict__ listG,
    const int* __restrict__ offG, const float* __restrict__ decayTotG,
    const float* __restrict__ nsG, float* __restrict__ sn)
{
    const int s = blockIdx.x >> 2;
    const int d = (blockIdx.x & 3) * 256 + threadIdx.x;
    float acc = decayTotG[s] * slots_in[s * DIM + d];
    const int k1 = offG[s + 1];
    for (int k = offG[s]; k < k1; ++k) {
        const int t = listG[k];
        acc = fmaf(coefG[k], wb[(size_t)t * DIM + d], acc);
    }
    sn[s * DIM + d] = acc * (1.0f / fmaxf(nsG[s], NORM_EPS));
}

// ===========================================================================
// OLD PATH (fallback if workspace is too small for G) — unchanged
// ===========================================================================

#define UPDATE_SLOT(i) { _Pragma("unroll") \
    for (int k = 0; k < 16; ++k) sreg[i][k] = MOM * sreg[i][k] + OMM * tv[k]; }

__global__ __launch_bounds__(256, 1) void scan_seq_kernel(
    const float* __restrict__ wb,
    const float* __restrict__ slots_in,
    const float* __restrict__ usage_in,
    float* __restrict__ sn_out,
    float* __restrict__ ns_out)
{
    const int tid = threadIdx.x;
    const int w = tid >> 6;
    const int j = tid & 63;

    __shared__ __align__(16) float tokL[DIM];
    __shared__ float ntp[4];
    __shared__ float simsL[NSLOTS];

    float sreg[8][16];
#pragma unroll
    for (int i = 0; i < 8; ++i) {
        const int s = 8 * w + i;
#pragma unroll
        for (int q = 0; q < 4; ++q) {
            float4 v = *(const float4*)&slots_in[s * DIM + 256 * q + 4 * j];
            sreg[i][4*q+0] = v.x; sreg[i][4*q+1] = v.y;
            sreg[i][4*q+2] = v.z; sreg[i][4*q+3] = v.w;
        }
    }
    float ssd;
    {
        float v[8];
#pragma unroll
        for (int i = 0; i < 8; ++i) {
            float a = 0.0f;
#pragma unroll
            for (int k = 0; k < 16; ++k) a = fmaf(sreg[i][k], sreg[i][k], a);
            v[i] = a;
        }
        ssd = reduce8(v, j);
    }
    unsigned emptyMask = 0;
    for (int s = 0; s < NSLOTS; ++s)
        if (usage_in[s] == 0.0f) emptyMask |= (1u << s);

    float4 gA = *(const float4*)&wb[0 * DIM + 4 * tid];
    float4 gB = *(const float4*)&wb[1 * DIM + 4 * tid];

#pragma unroll 1
    for (int t = 0; t < NTOK; ++t) {
        const float4 gc = gA;
        gA = gB;
        if (t + 2 < NTOK) gB = *(const float4*)&wb[(t + 2) * DIM + 4 * tid];

        *(float4*)&tokL[4 * tid] = gc;
        float s2 = gc.x*gc.x + gc.y*gc.y + gc.z*gc.z + gc.w*gc.w;
        s2 = reduce_all(s2);
        if (j == 0) ntp[w] = s2;
        __syncthreads();

        const float nt2 = ntp[0] + ntp[1] + ntp[2] + ntp[3];
        const float invnt = 1.0f / fmaxf(sqrtf(nt2), COS_EPS);

        float tv[16];
#pragma unroll
        for (int q = 0; q < 4; ++q) {
            float4 tq = *(const float4*)&tokL[256 * q + 4 * j];
            tv[4*q+0] = tq.x; tv[4*q+1] = tq.y; tv[4*q+2] = tq.z; tv[4*q+3] = tq.w;
        }
        float vv[8];
#pragma unroll
        for (int i = 0; i < 8; ++i) {
            float a = 0.0f;
#pragma unroll
            for (int k = 0; k < 16; ++k) a = fmaf(sreg[i][k], tv[k], a);
            vv[i] = a;
        }
        const float dotd = reduce8(vv, j);
        const float invd = 1.0f / fmaxf(sqrtf(ssd), COS_EPS);
        if ((j & 7) == 0) simsL[8 * w + (j >> 3)] = dotd * invd * invnt;
        __syncthreads();

        int idx;
        if (emptyMask) {
            idx = (int)__builtin_ctz(emptyMask);
            emptyMask &= ~(1u << idx);
        } else {
            float bv = simsL[j & 31];
            int bi = j & 31;
#pragma unroll
            for (int m = 1; m < 64; m <<= 1) {
                float ov = __shfl_xor(bv, m, 64);
                int   oi = __shfl_xor(bi, m, 64);
                if (ov > bv || (ov == bv && oi < bi)) { bv = ov; bi = oi; }
            }
            idx = bi;
        }

        if ((idx >> 3) == w) {
            switch (idx & 7) {
                case 0: UPDATE_SLOT(0); break;
                case 1: UPDATE_SLOT(1); break;
                case 2: UPDATE_SLOT(2); break;
                case 3: UPDATE_SLOT(3); break;
                case 4: UPDATE_SLOT(4); break;
                case 5: UPDATE_SLOT(5); break;
                case 6: UPDATE_SLOT(6); break;
                case 7: UPDATE_SLOT(7); break;
            }
            if ((j >> 3) == (idx & 7))
                ssd = MOM2 * ssd + MOMOMM2 * dotd + OMM2 * nt2;
        }
    }

    const float nsv = sqrtf(ssd);
    if ((j & 7) == 0) ns_out[8 * w + (j >> 3)] = nsv;
#pragma unroll
    for (int i = 0; i < 8; ++i) {
        const float ns_i = __shfl(nsv, i << 3, 64);
        const float inv_i = 1.0f / fmaxf(ns_i, NORM_EPS);
        const int s = 8 * w + i;
#pragma unroll
        for (int q = 0; q < 4; ++q) {
            float4 o;
            o.x = sreg[i][4*q+0] * inv_i;
            o.y = sreg[i][4*q+1] * inv_i;
            o.z = sreg[i][4*q+2] * inv_i;
            o.w = sreg[i][4*q+3] * inv_i;
            *(float4*)&sn_out[s * DIM + 256 * q + 4 * j] = o;
        }
    }
}

// ---------------------------------------------------------------------------
// Retrieve: unchanged.
// ---------------------------------------------------------------------------
__global__ __launch_bounds__(512, 2) void retrieve_kernel(
    const float* __restrict__ x,
    const float* __restrict__ sn_g,
    const float* __restrict__ ns_g,
    float* __restrict__ out)
{
    __shared__ __align__(16) float snL[8 * DIM];
    __shared__ float nsL[NSLOTS];
    __shared__ __align__(16) float scL[8 * 4 * NSLOTS];

    const int tid = threadIdx.x;
    const int w = tid >> 6;
    const int j = tid & 63;

    if (tid < NSLOTS) nsL[tid] = ns_g[tid];

    const int rowbase = (blockIdx.x * 8 + w) * 4;

    float xv[4][16];
#pragma unroll
    for (int r = 0; r < 4; ++r) {
        const float* xr = &x[(long)(rowbase + r) * DIM];
#pragma unroll
        for (int q = 0; q < 4; ++q) {
            float4 v = *(const float4*)&xr[256 * q + 4 * j];
            xv[r][4*q+0] = v.x; xv[r][4*q+1] = v.y;
            xv[r][4*q+2] = v.z; xv[r][4*q+3] = v.w;
        }
    }
    float mul[4];
#pragma unroll
    for (int r = 0; r < 4; ++r) {
        float a = 0.0f;
#pragma unroll
        for (int k = 0; k < 16; ++k) a = fmaf(xv[r][k], xv[r][k], a);
        a = reduce_all(a);
        mul[r] = (1.0f / fmaxf(sqrtf(a), NORM_EPS)) * INV_TEMP;
    }

#pragma unroll 1
    for (int h = 0; h < 4; ++h) {
        if (h) __syncthreads();
        for (int i = tid; i < 8 * DIM / 4; i += 512)
            *(float4*)&snL[4 * i] = *(const float4*)&sn_g[h * 8 * DIM + 4 * i];
        __syncthreads();
#pragma unroll 1
        for (int si = 0; si < 8; ++si) {
            const int s = 8 * h + si;
            float snv[16];
#pragma unroll
            for (int q = 0; q < 4; ++q) {
                float4 v = *(const float4*)&snL[si * DIM + 256 * q + 4 * j];
                snv[4*q+0]=v.x; snv[4*q+1]=v.y; snv[4*q+2]=v.z; snv[4*q+3]=v.w;
            }
            float p[4];
#pragma unroll
            for (int r = 0; r < 4; ++r) {
                float a = 0.0f;
#pragma unroll
                for (int k = 0; k < 16; ++k) a = fmaf(xv[r][k], snv[k], a);
                p[r] = a;
            }
            float d = reduce4(p, j);
            if ((j & 15) == 0) scL[w * 128 + (j >> 4) * 32 + s] = d;
        }
    }

    {
        const int r = j & 3;
        const float mulr = (r == 0) ? mul[0] : (r == 1) ? mul[1]
                         : (r == 2) ? mul[2] : mul[3];
        float sc[32];
#pragma unroll
        for (int s4 = 0; s4 < 8; ++s4) {
            float4 v = *(const float4*)&scL[w * 128 + r * 32 + 4 * s4];
            sc[4*s4+0]=v.x; sc[4*s4+1]=v.y; sc[4*s4+2]=v.z; sc[4*s4+3]=v.w;
        }
        float m = -INFINITY;
#pragma unroll
        for (int s = 0; s < 32; ++s) { sc[s] *= mulr; m = fmaxf(m, sc[s]); }
        float sum = 0.0f;
#pragma unroll
        for (int s = 0; s < 32; ++s) { sc[s] = expf(sc[s] - m); sum += sc[s]; }
        const float isum = 1.0f / sum;
        if (j < 4) {
#pragma unroll
            for (int s4 = 0; s4 < 8; ++s4) {
                float4 o;
                o.x = sc[4*s4+0] * isum * nsL[4*s4+0];
                o.y = sc[4*s4+1] * isum * nsL[4*s4+1];
                o.z = sc[4*s4+2] * isum * nsL[4*s4+2];
                o.w = sc[4*s4+3] * isum * nsL[4*s4+3];
                *(float4*)&scL[w * 128 + j * 32 + 4 * s4] = o;
            }
        }
    }

    float acc[4][16];
#pragma unroll
    for (int r = 0; r < 4; ++r)
#pragma unroll
        for (int k = 0; k < 16; ++k) acc[r][k] = 0.0f;

#pragma unroll 1
    for (int h = 3; h >= 0; --h) {
        if (h != 3) {
            __syncthreads();
            for (int i = tid; i < 8 * DIM / 4; i += 512)
                *(float4*)&snL[4 * i] = *(const float4*)&sn_g[h * 8 * DIM + 4 * i];
            __syncthreads();
        }
#pragma unroll 1
        for (int si = 0; si < 8; ++si) {
            const int s = 8 * h + si;
            float snv[16];
#pragma unroll
            for (int q = 0; q < 4; ++q) {
                float4 v = *(const float4*)&snL[si * DIM + 256 * q + 4 * j];
                snv[4*q+0]=v.x; snv[4*q+1]=v.y; snv[4*q+2]=v.z; snv[4*q+3]=v.w;
            }
#pragma unroll
            for (int r = 0; r < 4; ++r) {
                const float ww = scL[w * 128 + r * 32 + s];
#pragma unroll
                for (int k = 0; k < 16; ++k) acc[r][k] = fmaf(ww, snv[k], acc[r][k]);
            }
        }
    }

#pragma unroll
    for (int r = 0; r < 4; ++r) {
        float* orow = &out[(long)(rowbase + r) * DIM];
#pragma unroll
        for (int q = 0; q < 4; ++q) {
            float4 o;
            o.x = acc[r][4*q+0]; o.y = acc[r][4*q+1];
            o.z = acc[r][4*q+2]; o.w = acc[r][4*q+3];
            *(float4*)&orow[256 * q + 4 * j] = o;
        }
    }
}

extern "C" void kernel_launch(void* const* d_in, const int* in_sizes, int n_in,
                              void* d_out, int out_size, void* d_ws, size_t ws_size,
                              hipStream_t stream) {
    const float* x  = (const float*)d_in[0];   // [4,8192,1024]
    const float* wb = (const float*)d_in[1];   // [2048,1024]
    const float* sl = (const float*)d_in[2];   // [32,1024]
    const float* us = (const float*)d_in[3];   // [32]
    float* out = (float*)d_out;

    // workspace layout (floats)
    float* sn   = (float*)d_ws;                    // 32*1024
    float* nsG  = sn + NSLOTS * DIM;               // 32 (pad 64)
    float* D    = nsG + 64;                        // 32*2048
    float* G    = D + NSLOTS * NTOK;               // 2048*2048
    float* coefG = G + (size_t)NTOK * NTOK;        // 2048
    int* listG  = (int*)(coefG + NTOK);            // 2048
    int* offG   = listG + NTOK;                    // 33 (pad 64)
    float* decayTotG = (float*)(offG + 64);        // 32
    const size_t ws_need = (size_t)((decayTotG + 64) - sn) * sizeof(float);

    if (ws_size >= ws_need) {
        gram_kernel<<<dim3(136 * 4), dim3(256), 0, stream>>>(wb, G);
        slotdot_kernel<<<dim3(256), dim3(256), 0, stream>>>(wb, sl, D);
        scan_kernel<<<dim3(1), dim3(512), 0, stream>>>(
            sl, us, G, D, listG, coefG, offG, decayTotG, nsG);
        mat_kernel<<<dim3(128), dim3(256), 0, stream>>>(
            wb, sl, coefG, listG, offG, decayTotG, nsG, sn);
    } else {
        // fallback: proven sequential path
        scan_seq_kernel<<<dim3(1), dim3(256), 0, stream>>>(wb, sl, us, sn, nsG);
    }
    retrieve_kernel<<<dim3(NROWS / 32), dim3(512), 0, stream>>>(x, sn, nsG, out);
}